// Round 1
// baseline (1968.933 us; speedup 1.0000x reference)
//
#include <hip/hip_runtime.h>
#include <math.h>

constexpr int BATCH = 8;
constexpr int SEQ   = 1024;
constexpr int DM    = 256;
constexpr int DF    = 2048;
constexpr int NH    = 8;
constexpr int HDIM  = 32;
constexpr int ROWS  = BATCH * SEQ;    // 8192
constexpr float NEGV = -9e15f;
constexpr float EPSV = 1e-5f;

// ---------------- GEMM: C = A(M,K) @ B +bias +relu ----------------
// BT=false: B is (K,N) row-major.  BT=true: B is (N,K) row-major (i.e. A@B^T).
// Requires M%64==0, N%64==0, K%16==0 (all shapes here satisfy this).
template<bool BT, bool BIAS, bool RELU>
__global__ __launch_bounds__(256) void gemm_k(const float* __restrict__ A,
                                              const float* __restrict__ Bm,
                                              const float* __restrict__ bias,
                                              float* __restrict__ C,
                                              int Mm, int Nn, int Kk)
{
    __shared__ float As[16][65];
    __shared__ float Bs[16][65];
    const int t  = threadIdx.x;
    const int m0 = blockIdx.y * 64;
    const int n0 = blockIdx.x * 64;
    const int cm = (t >> 4) << 2;   // compute row base within tile
    const int cn = (t & 15) << 2;   // compute col base within tile
    float acc[4][4] = {};

    for (int k0 = 0; k0 < Kk; k0 += 16) {
        {   // load A tile 64x16 (transposed into As[k][m])
            int kx = t & 15, my = t >> 4;
            #pragma unroll
            for (int i = 0; i < 4; i++)
                As[kx][my + 16*i] = A[(size_t)(m0 + my + 16*i) * Kk + k0 + kx];
        }
        if (!BT) {
            int nx = t & 63, ky = t >> 6;
            #pragma unroll
            for (int i = 0; i < 4; i++)
                Bs[ky + 4*i][nx] = Bm[(size_t)(k0 + ky + 4*i) * Nn + n0 + nx];
        } else {
            int kx = t & 15, ny = t >> 4;
            #pragma unroll
            for (int i = 0; i < 4; i++)
                Bs[kx][ny + 16*i] = Bm[(size_t)(n0 + ny + 16*i) * Kk + k0 + kx];
        }
        __syncthreads();
        #pragma unroll
        for (int k = 0; k < 16; k++) {
            float a[4], bb[4];
            #pragma unroll
            for (int i = 0; i < 4; i++) a[i]  = As[k][cm + i];
            #pragma unroll
            for (int j = 0; j < 4; j++) bb[j] = Bs[k][cn + j];
            #pragma unroll
            for (int i = 0; i < 4; i++)
                #pragma unroll
                for (int j = 0; j < 4; j++)
                    acc[i][j] = fmaf(a[i], bb[j], acc[i][j]);
        }
        __syncthreads();
    }
    #pragma unroll
    for (int i = 0; i < 4; i++) {
        int row = m0 + cm + i;
        #pragma unroll
        for (int j = 0; j < 4; j++) {
            int col = n0 + cn + j;
            float v = acc[i][j];
            if (BIAS) v += bias[col];
            if (RELU) v = fmaxf(v, 0.f);
            C[(size_t)row * Nn + col] = v;
        }
    }
}

// ---------------- LayerNorm(a + r) * g + b, row = 256 elems ----------------
__global__ __launch_bounds__(64) void ln_k(const float* __restrict__ a,
                                           const float* __restrict__ r,
                                           const float* __restrict__ g,
                                           const float* __restrict__ be,
                                           float* __restrict__ o)
{
    size_t row = blockIdx.x;
    int t = threadIdx.x;
    const float* pa = a + row * DM;
    const float* pr = r + row * DM;
    float v[4]; float s = 0.f;
    #pragma unroll
    for (int i = 0; i < 4; i++) { v[i] = pa[t + 64*i] + pr[t + 64*i]; s += v[i]; }
    #pragma unroll
    for (int off = 32; off; off >>= 1) s += __shfl_xor(s, off, 64);
    float mu = s * (1.0f / DM);
    float q = 0.f;
    #pragma unroll
    for (int i = 0; i < 4; i++) { float d = v[i] - mu; q += d * d; }
    #pragma unroll
    for (int off = 32; off; off >>= 1) q += __shfl_xor(q, off, 64);
    float rs = rsqrtf(q * (1.0f / DM) + EPSV);
    #pragma unroll
    for (int i = 0; i < 4; i++) {
        int c = t + 64*i;
        o[row * DM + c] = (v[i] - mu) * rs * g[c] + be[c];
    }
}

// ---------------- f1 = Wh@a1, f2 = Wh@a2 (per row) ----------------
__global__ __launch_bounds__(64) void f12_k(const float* __restrict__ Wh,
                                            const float* __restrict__ a_gat,
                                            float* __restrict__ f1,
                                            float* __restrict__ f2)
{
    size_t row = blockIdx.x;
    int t = threadIdx.x;
    float s1 = 0.f, s2 = 0.f;
    #pragma unroll
    for (int i = 0; i < 4; i++) {
        float w = Wh[row * DM + t + 64*i];
        s1 = fmaf(w, a_gat[t + 64*i], s1);
        s2 = fmaf(w, a_gat[DM + t + 64*i], s2);
    }
    #pragma unroll
    for (int off = 32; off; off >>= 1) {
        s1 += __shfl_xor(s1, off, 64);
        s2 += __shfl_xor(s2, off, 64);
    }
    if (t == 0) { f1[row] = s1; f2[row] = s2; }
}

// ---------------- GAT: row softmax over masked e, then p @ Wh, elu ----------------
__global__ __launch_bounds__(256) void gat_k(const float* __restrict__ Wh,
                                             const int* __restrict__ adj,
                                             const float* __restrict__ f1,
                                             const float* __restrict__ f2,
                                             float* __restrict__ out)
{
    __shared__ float p[SEQ];
    __shared__ float red[4];
    int b = blockIdx.x >> 10;
    int t = threadIdx.x;
    float f1i = f1[blockIdx.x];
    const int* arow = adj + ((size_t)blockIdx.x << 10);

    float e[4];
    float lmax = -3.4e38f;
    #pragma unroll
    for (int u = 0; u < 4; u++) {
        int j = t + (u << 8);
        e[u] = (arow[j] > 0) ? (f1i + f2[(b << 10) + j]) : NEGV;
        lmax = fmaxf(lmax, e[u]);
    }
    #pragma unroll
    for (int off = 32; off; off >>= 1) lmax = fmaxf(lmax, __shfl_xor(lmax, off, 64));
    if ((t & 63) == 0) red[t >> 6] = lmax;
    __syncthreads();
    float mx = fmaxf(fmaxf(red[0], red[1]), fmaxf(red[2], red[3]));
    __syncthreads();
    float ex[4]; float lsum = 0.f;
    #pragma unroll
    for (int u = 0; u < 4; u++) { ex[u] = __expf(e[u] - mx); lsum += ex[u]; }
    #pragma unroll
    for (int off = 32; off; off >>= 1) lsum += __shfl_xor(lsum, off, 64);
    if ((t & 63) == 0) red[t >> 6] = lsum;
    __syncthreads();
    float inv = 1.0f / (red[0] + red[1] + red[2] + red[3]);
    #pragma unroll
    for (int u = 0; u < 4; u++) p[t + (u << 8)] = ex[u] * inv;
    __syncthreads();

    const float* whb = Wh + ((size_t)(b << 10)) * DM;
    float acc = 0.f;
    for (int j = 0; j < SEQ; j += 4) {
        acc = fmaf(p[j],     whb[(size_t)(j    ) * DM + t], acc);
        acc = fmaf(p[j + 1], whb[(size_t)(j + 1) * DM + t], acc);
        acc = fmaf(p[j + 2], whb[(size_t)(j + 2) * DM + t], acc);
        acc = fmaf(p[j + 3], whb[(size_t)(j + 3) * DM + t], acc);
    }
    // elu
    out[((size_t)blockIdx.x) * DM + t] = acc > 0.f ? acc : expm1f(acc);
}

// ---------------- MHA: 8 query rows per block, fused softmax, ctx out ----------------
__global__ __launch_bounds__(256) void mha_k(const float* __restrict__ qkv,
                                             float* __restrict__ ctx)
{
    __shared__ float sc[8][SEQ];   // 32 KB
    __shared__ float qs[8][HDIM];
    int blk = blockIdx.x;
    int it = blk & 127;
    int h  = (blk >> 7) & 7;
    int b  = blk >> 10;
    int i0 = it << 3;
    int t = threadIdx.x;
    int r = t >> 5, l = t & 31;

    qs[r][l] = qkv[((size_t)(b * SEQ) + i0 + r) * 768 + h * HDIM + l];
    __syncthreads();

    const float* kbase = qkv + (size_t)b * SEQ * 768 + 256 + h * HDIM;
    for (int u = 0; u < 32; u++) {
        int j = l + (u << 5);
        const float* krow = kbase + (size_t)j * 768;
        float s = 0.f;
        #pragma unroll
        for (int c = 0; c < HDIM; c++) s = fmaf(qs[r][c], krow[c], s);
        sc[r][j] = s * 0.17677669529663687f;   // 1/sqrt(32)
    }
    // each thread wrote exactly the elements it now reads (j = l+32u): no sync needed
    float mx = -3.4e38f;
    for (int u = 0; u < 32; u++) mx = fmaxf(mx, sc[r][l + (u << 5)]);
    #pragma unroll
    for (int off = 16; off; off >>= 1) mx = fmaxf(mx, __shfl_xor(mx, off, 32));
    float sum = 0.f;
    for (int u = 0; u < 32; u++) {
        float e = __expf(sc[r][l + (u << 5)] - mx);
        sc[r][l + (u << 5)] = e;
        sum += e;
    }
    #pragma unroll
    for (int off = 16; off; off >>= 1) sum += __shfl_xor(sum, off, 32);
    float inv = 1.0f / sum;
    __syncthreads();

    const float* vbase = qkv + (size_t)b * SEQ * 768 + 512 + h * HDIM + l;
    float acc = 0.f;
    for (int j = 0; j < SEQ; j += 4) {
        acc = fmaf(sc[r][j],     vbase[(size_t)(j    ) * 768], acc);
        acc = fmaf(sc[r][j + 1], vbase[(size_t)(j + 1) * 768], acc);
        acc = fmaf(sc[r][j + 2], vbase[(size_t)(j + 2) * 768], acc);
        acc = fmaf(sc[r][j + 3], vbase[(size_t)(j + 3) * 768], acc);
    }
    ctx[((size_t)(b * SEQ) + i0 + r) * DM + h * HDIM + l] = acc * inv;
}

extern "C" void kernel_launch(void* const* d_in, const int* in_sizes, int n_in,
                              void* d_out, int out_size, void* d_ws, size_t ws_size,
                              hipStream_t stream)
{
    const float* src        = (const float*)d_in[0];
    const int*   adj        = (const int*)  d_in[1];
    const float* W_gat      = (const float*)d_in[2];
    const float* a_gat      = (const float*)d_in[3];
    const float* in_proj_w  = (const float*)d_in[4];
    const float* in_proj_b  = (const float*)d_in[5];
    const float* out_proj_w = (const float*)d_in[6];
    const float* out_proj_b = (const float*)d_in[7];
    const float* lin1_w     = (const float*)d_in[8];
    const float* lin1_b     = (const float*)d_in[9];
    const float* lin2_w     = (const float*)d_in[10];
    const float* lin2_b     = (const float*)d_in[11];
    const float* ln1_g      = (const float*)d_in[12];
    const float* ln1_b_     = (const float*)d_in[13];
    const float* ln2_g      = (const float*)d_in[14];
    const float* ln2_b_     = (const float*)d_in[15];
    const float* ln3_g      = (const float*)d_in[16];
    const float* ln3_b_     = (const float*)d_in[17];

    float* ws  = (float*)d_ws;
    float* Wh  = ws + 0;          // 2M floats (later reused for ctx)
    float* tmp = ws + 2097152;    // 2M (graph_out / attn_out / ff2)
    float* x   = ws + 4194304;    // 2M
    float* big = ws + 6291456;    // 16M (qkv first 6M, then ff1)
    float* y   = ws + 23068672;   // 2M
    float* f1  = ws + 25165824;   // 8K
    float* f2  = f1 + ROWS;       // 8K

    dim3 b256(256), b64(64);

    // 1. Wh = src @ W_gat              (NN, 8192x256x256)
    gemm_k<false,false,false><<<dim3(DM/64, ROWS/64), b256, 0, stream>>>(src, W_gat, nullptr, Wh, ROWS, DM, DM);
    // 2. f1/f2
    f12_k<<<ROWS, b64, 0, stream>>>(Wh, a_gat, f1, f2);
    // 3. GAT attention + elu -> tmp
    gat_k<<<ROWS, b256, 0, stream>>>(Wh, adj, f1, f2, tmp);
    // 4. x = LN(src + graph_out)
    ln_k<<<ROWS, b64, 0, stream>>>(src, tmp, ln1_g, ln1_b_, x);
    // 5. qkv = x @ in_proj_w^T + b     (NT, 8192x768x256)
    gemm_k<true,true,false><<<dim3(768/64, ROWS/64), b256, 0, stream>>>(x, in_proj_w, in_proj_b, big, ROWS, 768, DM);
    // 6. MHA -> ctx (reuse Wh buffer)
    mha_k<<<8192, b256, 0, stream>>>(big, Wh);
    // 7. attn_out = ctx @ out_proj_w^T + b
    gemm_k<true,true,false><<<dim3(DM/64, ROWS/64), b256, 0, stream>>>(Wh, out_proj_w, out_proj_b, tmp, ROWS, DM, DM);
    // 8. y = LN(x + attn_out)
    ln_k<<<ROWS, b64, 0, stream>>>(x, tmp, ln2_g, ln2_b_, y);
    // 9. ff1 = relu(y @ lin1_w^T + b)  (NT, 8192x2048x256)
    gemm_k<true,true,true><<<dim3(DF/64, ROWS/64), b256, 0, stream>>>(y, lin1_w, lin1_b, big, ROWS, DF, DM);
    // 10. ff2 = ff1 @ lin2_w^T + b     (NT, 8192x256x2048)
    gemm_k<true,true,false><<<dim3(DM/64, ROWS/64), b256, 0, stream>>>(big, lin2_w, lin2_b, tmp, ROWS, DM, DF);
    // 11. out = LN(y + ff2)
    ln_k<<<ROWS, b64, 0, stream>>>(y, tmp, ln3_g, ln3_b_, (float*)d_out);
}

// Round 2
// 1013.448 us; speedup vs baseline: 1.9428x; 1.9428x over previous
//
#include <hip/hip_runtime.h>
#include <math.h>

constexpr int BATCH = 8;
constexpr int SEQ   = 1024;
constexpr int DM    = 256;
constexpr int DF    = 2048;
constexpr int NH    = 8;
constexpr int HDIM  = 32;
constexpr int ROWS  = BATCH * SEQ;    // 8192
constexpr float NEGV = -9e15f;
constexpr float EPSV = 1e-5f;

// ---------------- GEMM: C = A(M,K) @ B +bias +relu ----------------
template<bool BT, bool BIAS, bool RELU>
__global__ __launch_bounds__(256) void gemm_k(const float* __restrict__ A,
                                              const float* __restrict__ Bm,
                                              const float* __restrict__ bias,
                                              float* __restrict__ C,
                                              int Mm, int Nn, int Kk)
{
    __shared__ float As[16][65];
    __shared__ float Bs[16][65];
    const int t  = threadIdx.x;
    const int m0 = blockIdx.y * 64;
    const int n0 = blockIdx.x * 64;
    const int cm = (t >> 4) << 2;
    const int cn = (t & 15) << 2;
    float acc[4][4] = {};

    for (int k0 = 0; k0 < Kk; k0 += 16) {
        {
            int kx = t & 15, my = t >> 4;
            #pragma unroll
            for (int i = 0; i < 4; i++)
                As[kx][my + 16*i] = A[(size_t)(m0 + my + 16*i) * Kk + k0 + kx];
        }
        if (!BT) {
            int nx = t & 63, ky = t >> 6;
            #pragma unroll
            for (int i = 0; i < 4; i++)
                Bs[ky + 4*i][nx] = Bm[(size_t)(k0 + ky + 4*i) * Nn + n0 + nx];
        } else {
            int kx = t & 15, ny = t >> 4;
            #pragma unroll
            for (int i = 0; i < 4; i++)
                Bs[kx][ny + 16*i] = Bm[(size_t)(n0 + ny + 16*i) * Kk + k0 + kx];
        }
        __syncthreads();
        #pragma unroll
        for (int k = 0; k < 16; k++) {
            float a[4], bb[4];
            #pragma unroll
            for (int i = 0; i < 4; i++) a[i]  = As[k][cm + i];
            #pragma unroll
            for (int j = 0; j < 4; j++) bb[j] = Bs[k][cn + j];
            #pragma unroll
            for (int i = 0; i < 4; i++)
                #pragma unroll
                for (int j = 0; j < 4; j++)
                    acc[i][j] = fmaf(a[i], bb[j], acc[i][j]);
        }
        __syncthreads();
    }
    #pragma unroll
    for (int i = 0; i < 4; i++) {
        int row = m0 + cm + i;
        #pragma unroll
        for (int j = 0; j < 4; j++) {
            int col = n0 + cn + j;
            float v = acc[i][j];
            if (BIAS) v += bias[col];
            if (RELU) v = fmaxf(v, 0.f);
            C[(size_t)row * Nn + col] = v;
        }
    }
}

// ---------------- LayerNorm(a + r) * g + b ----------------
__global__ __launch_bounds__(64) void ln_k(const float* __restrict__ a,
                                           const float* __restrict__ r,
                                           const float* __restrict__ g,
                                           const float* __restrict__ be,
                                           float* __restrict__ o)
{
    size_t row = blockIdx.x;
    int t = threadIdx.x;
    const float* pa = a + row * DM;
    const float* pr = r + row * DM;
    float v[4]; float s = 0.f;
    #pragma unroll
    for (int i = 0; i < 4; i++) { v[i] = pa[t + 64*i] + pr[t + 64*i]; s += v[i]; }
    #pragma unroll
    for (int off = 32; off; off >>= 1) s += __shfl_xor(s, off, 64);
    float mu = s * (1.0f / DM);
    float q = 0.f;
    #pragma unroll
    for (int i = 0; i < 4; i++) { float d = v[i] - mu; q += d * d; }
    #pragma unroll
    for (int off = 32; off; off >>= 1) q += __shfl_xor(q, off, 64);
    float rs = rsqrtf(q * (1.0f / DM) + EPSV);
    #pragma unroll
    for (int i = 0; i < 4; i++) {
        int c = t + 64*i;
        o[row * DM + c] = (v[i] - mu) * rs * g[c] + be[c];
    }
}

// ---------------- f1 = Wh@a1, f2 = Wh@a2 ----------------
__global__ __launch_bounds__(64) void f12_k(const float* __restrict__ Wh,
                                            const float* __restrict__ a_gat,
                                            float* __restrict__ f1,
                                            float* __restrict__ f2)
{
    size_t row = blockIdx.x;
    int t = threadIdx.x;
    float s1 = 0.f, s2 = 0.f;
    #pragma unroll
    for (int i = 0; i < 4; i++) {
        float w = Wh[row * DM + t + 64*i];
        s1 = fmaf(w, a_gat[t + 64*i], s1);
        s2 = fmaf(w, a_gat[DM + t + 64*i], s2);
    }
    #pragma unroll
    for (int off = 32; off; off >>= 1) {
        s1 += __shfl_xor(s1, off, 64);
        s2 += __shfl_xor(s2, off, 64);
    }
    if (t == 0) { f1[row] = s1; f2[row] = s2; }
}

// ---------------- GAT v2: 8 output rows / block, Wh tiles staged in LDS ----------------
__global__ __launch_bounds__(256) void gat_k(const float* __restrict__ Wh,
                                             const int* __restrict__ adj,
                                             const float* __restrict__ f1,
                                             const float* __restrict__ f2,
                                             float* __restrict__ out)
{
    __shared__ float p[8][SEQ];      // 32 KB, normalized probs
    __shared__ float Ws[16][264];    // staged Wh tile (+8 pad: 2-way-free b64 reads)
    const int i0 = blockIdx.x << 3;  // first of 8 output rows
    const int b  = i0 >> 10;
    const int t  = threadIdx.x;
    const int r  = t >> 5;           // row 0..7
    const int l  = t & 31;           // lane-in-group

    // --- masked softmax row (f1[i] + f2[j]) ---
    const int* arow = adj + (size_t)(i0 + r) * SEQ;
    const float* f2b = f2 + ((size_t)b << 10);
    const float f1i = f1[i0 + r];
    float ex[32];
    float mx = -3.4e38f;
    #pragma unroll
    for (int u = 0; u < 32; u++) {
        int j = l + (u << 5);
        float e = (arow[j] > 0) ? (f1i + f2b[j]) : NEGV;
        ex[u] = e; mx = fmaxf(mx, e);
    }
    #pragma unroll
    for (int off = 16; off; off >>= 1) mx = fmaxf(mx, __shfl_xor(mx, off, 32));
    float sum = 0.f;
    #pragma unroll
    for (int u = 0; u < 32; u++) { ex[u] = __expf(ex[u] - mx); sum += ex[u]; }
    #pragma unroll
    for (int off = 16; off; off >>= 1) sum += __shfl_xor(sum, off, 32);
    float inv = 1.0f / sum;
    #pragma unroll
    for (int u = 0; u < 32; u++) p[r][l + (u << 5)] = ex[u] * inv;
    __syncthreads();

    // --- O = p @ Wh, tiles of 16 j-rows staged in LDS ---
    float acc[8] = {};
    const int srow = t >> 4, scb = (t & 15) << 2;
    for (int j0 = 0; j0 < SEQ; j0 += 16) {
        const float* wrow = Wh + ((size_t)((b << 10) + j0 + srow)) * DM;
        #pragma unroll
        for (int q = 0; q < 4; q++)
            *(float4*)&Ws[srow][scb + 64*q] = *(const float4*)&wrow[scb + 64*q];
        __syncthreads();
        #pragma unroll
        for (int jj = 0; jj < 16; jj++) {
            float pr = p[r][j0 + jj];
            #pragma unroll
            for (int u = 0; u < 4; u++) {
                float2 w = *(const float2*)&Ws[jj][2*l + 64*u];
                acc[2*u]   = fmaf(pr, w.x, acc[2*u]);
                acc[2*u+1] = fmaf(pr, w.y, acc[2*u+1]);
            }
        }
        __syncthreads();
    }
    // elu + store (float2, coalesced)
    float* orow = out + (size_t)(i0 + r) * DM;
    #pragma unroll
    for (int u = 0; u < 4; u++) {
        float2 o;
        o.x = acc[2*u]   > 0.f ? acc[2*u]   : expm1f(acc[2*u]);
        o.y = acc[2*u+1] > 0.f ? acc[2*u+1] : expm1f(acc[2*u+1]);
        *(float2*)&orow[2*l + 64*u] = o;
    }
}

// ---------------- MHA v2: flash-style, 64 q-rows per block ----------------
__global__ __launch_bounds__(256) void mha_k(const float* __restrict__ qkv,
                                             float* __restrict__ ctx)
{
    __shared__ float Qs[64][36];   // Q tile (pre-scaled), broadcast reads
    __shared__ float Kt[32][68];   // K tile TRANSPOSED: Kt[k][jcol]
    __shared__ float Vs[64][36];   // V tile row-major
    __shared__ float Ps[64][68];   // probs tile (stride 68: 2-way writes, aligned b128 reads)

    const int blk = blockIdx.x;          // b*128 + h*16 + qt
    const int qt = blk & 15;
    const int h  = (blk >> 4) & 7;
    const int b  = blk >> 7;
    const int i0 = qt << 6;
    const int t  = threadIdx.x;
    const int g  = t >> 4;               // 0..15: row group (4 rows)
    const int c  = t & 15;               // col lane
    const size_t base = (size_t)b * SEQ * 768;

    {   // load Q tile, fold in 1/sqrt(hd)
        const int row = t >> 2, cb = (t & 3) << 3;
        const float* src = qkv + base + (size_t)(i0 + row) * 768 + h * HDIM + cb;
        const float s = 0.17677669529663687f;
        float4 v0 = *(const float4*)src, v1 = *(const float4*)(src + 4);
        v0.x*=s; v0.y*=s; v0.z*=s; v0.w*=s; v1.x*=s; v1.y*=s; v1.z*=s; v1.w*=s;
        *(float4*)&Qs[row][cb]     = v0;
        *(float4*)&Qs[row][cb + 4] = v1;
    }

    float m_run[4], l_run[4], Oa[4][2];
    #pragma unroll
    for (int i = 0; i < 4; i++) { m_run[i] = -3.4e38f; l_run[i] = 0.f; Oa[i][0] = 0.f; Oa[i][1] = 0.f; }

    for (int j0 = 0; j0 < SEQ; j0 += 64) {
        __syncthreads();
        {   // stage K (transposed) and V
            const int row = t >> 2, cb = (t & 3) << 3;
            const float* kp = qkv + base + (size_t)(j0 + row) * 768 + 256 + h * HDIM + cb;
            float4 k0 = *(const float4*)kp, k1 = *(const float4*)(kp + 4);
            Kt[cb+0][row] = k0.x; Kt[cb+1][row] = k0.y; Kt[cb+2][row] = k0.z; Kt[cb+3][row] = k0.w;
            Kt[cb+4][row] = k1.x; Kt[cb+5][row] = k1.y; Kt[cb+6][row] = k1.z; Kt[cb+7][row] = k1.w;
            const float* vp = qkv + base + (size_t)(j0 + row) * 768 + 512 + h * HDIM + cb;
            *(float4*)&Vs[row][cb]     = *(const float4*)vp;
            *(float4*)&Vs[row][cb + 4] = *(const float4*)(vp + 4);
        }
        __syncthreads();

        // S[4][4] = Q(rows 4g+i) · K^T(cols c+16j)
        float S[4][4] = {};
        #pragma unroll
        for (int k0 = 0; k0 < HDIM; k0 += 4) {
            float4 qv[4];
            #pragma unroll
            for (int i = 0; i < 4; i++) qv[i] = *(const float4*)&Qs[4*g + i][k0];
            #pragma unroll
            for (int kk = 0; kk < 4; kk++) {
                float kv[4];
                #pragma unroll
                for (int j = 0; j < 4; j++) kv[j] = Kt[k0 + kk][c + 16*j];
                #pragma unroll
                for (int i = 0; i < 4; i++) {
                    float qe = (&qv[i].x)[kk];
                    #pragma unroll
                    for (int j = 0; j < 4; j++) S[i][j] = fmaf(qe, kv[j], S[i][j]);
                }
            }
        }

        // online softmax update (rows reduced across the 16 lanes sharing g)
        #pragma unroll
        for (int i = 0; i < 4; i++) {
            float tmax = fmaxf(fmaxf(S[i][0], S[i][1]), fmaxf(S[i][2], S[i][3]));
            #pragma unroll
            for (int off = 8; off; off >>= 1) tmax = fmaxf(tmax, __shfl_xor(tmax, off, 16));
            float mnew = fmaxf(m_run[i], tmax);
            float sc = __expf(m_run[i] - mnew);
            m_run[i] = mnew;
            float rs = 0.f;
            #pragma unroll
            for (int j = 0; j < 4; j++) { S[i][j] = __expf(S[i][j] - mnew); rs += S[i][j]; }
            #pragma unroll
            for (int off = 8; off; off >>= 1) rs += __shfl_xor(rs, off, 16);
            l_run[i] = l_run[i] * sc + rs;
            Oa[i][0] *= sc; Oa[i][1] *= sc;
            #pragma unroll
            for (int j = 0; j < 4; j++) Ps[4*g + i][c + 16*j] = S[i][j];
        }
        __syncthreads();

        // O(rows 4g+i, cols 2c..2c+1) += P · V
        #pragma unroll
        for (int jj0 = 0; jj0 < 64; jj0 += 4) {
            float4 pv[4];
            #pragma unroll
            for (int i = 0; i < 4; i++) pv[i] = *(const float4*)&Ps[4*g + i][jj0];
            #pragma unroll
            for (int q = 0; q < 4; q++) {
                float2 vv = *(const float2*)&Vs[jj0 + q][2*c];
                #pragma unroll
                for (int i = 0; i < 4; i++) {
                    float pe = (&pv[i].x)[q];
                    Oa[i][0] = fmaf(pe, vv.x, Oa[i][0]);
                    Oa[i][1] = fmaf(pe, vv.y, Oa[i][1]);
                }
            }
        }
    }

    #pragma unroll
    for (int i = 0; i < 4; i++) {
        float inv = 1.0f / l_run[i];
        size_t row = (size_t)(b * SEQ) + i0 + 4*g + i;
        float2 o; o.x = Oa[i][0] * inv; o.y = Oa[i][1] * inv;
        *(float2*)&ctx[row * DM + h * HDIM + 2*c] = o;
    }
}

extern "C" void kernel_launch(void* const* d_in, const int* in_sizes, int n_in,
                              void* d_out, int out_size, void* d_ws, size_t ws_size,
                              hipStream_t stream)
{
    const float* src        = (const float*)d_in[0];
    const int*   adj        = (const int*)  d_in[1];
    const float* W_gat      = (const float*)d_in[2];
    const float* a_gat      = (const float*)d_in[3];
    const float* in_proj_w  = (const float*)d_in[4];
    const float* in_proj_b  = (const float*)d_in[5];
    const float* out_proj_w = (const float*)d_in[6];
    const float* out_proj_b = (const float*)d_in[7];
    const float* lin1_w     = (const float*)d_in[8];
    const float* lin1_b     = (const float*)d_in[9];
    const float* lin2_w     = (const float*)d_in[10];
    const float* lin2_b     = (const float*)d_in[11];
    const float* ln1_g      = (const float*)d_in[12];
    const float* ln1_b_     = (const float*)d_in[13];
    const float* ln2_g      = (const float*)d_in[14];
    const float* ln2_b_     = (const float*)d_in[15];
    const float* ln3_g      = (const float*)d_in[16];
    const float* ln3_b_     = (const float*)d_in[17];

    float* ws  = (float*)d_ws;
    float* Wh  = ws + 0;          // 2M floats (later reused for ctx)
    float* tmp = ws + 2097152;    // 2M
    float* x   = ws + 4194304;    // 2M
    float* big = ws + 6291456;    // 16M (qkv then ff1)
    float* y   = ws + 23068672;   // 2M
    float* f1  = ws + 25165824;
    float* f2  = f1 + ROWS;

    dim3 b256(256), b64(64);

    gemm_k<false,false,false><<<dim3(DM/64, ROWS/64), b256, 0, stream>>>(src, W_gat, nullptr, Wh, ROWS, DM, DM);
    f12_k<<<ROWS, b64, 0, stream>>>(Wh, a_gat, f1, f2);
    gat_k<<<ROWS/8, b256, 0, stream>>>(Wh, adj, f1, f2, tmp);
    ln_k<<<ROWS, b64, 0, stream>>>(src, tmp, ln1_g, ln1_b_, x);
    gemm_k<true,true,false><<<dim3(768/64, ROWS/64), b256, 0, stream>>>(x, in_proj_w, in_proj_b, big, ROWS, 768, DM);
    mha_k<<<BATCH*NH*(SEQ/64), b256, 0, stream>>>(big, Wh);
    gemm_k<true,true,false><<<dim3(DM/64, ROWS/64), b256, 0, stream>>>(Wh, out_proj_w, out_proj_b, tmp, ROWS, DM, DM);
    ln_k<<<ROWS, b64, 0, stream>>>(x, tmp, ln2_g, ln2_b_, y);
    gemm_k<true,true,true><<<dim3(DF/64, ROWS/64), b256, 0, stream>>>(y, lin1_w, lin1_b, big, ROWS, DF, DM);
    gemm_k<true,true,false><<<dim3(DM/64, ROWS/64), b256, 0, stream>>>(big, lin2_w, lin2_b, tmp, ROWS, DM, DF);
    ln_k<<<ROWS, b64, 0, stream>>>(y, tmp, ln3_g, ln3_b_, (float*)d_out);
}

// Round 3
// 371.739 us; speedup vs baseline: 5.2965x; 2.7262x over previous
//
#include <hip/hip_runtime.h>
#include <math.h>

constexpr int BATCH = 8;
constexpr int SEQ   = 1024;
constexpr int DM    = 256;
constexpr int DF    = 2048;
constexpr int NH    = 8;
constexpr int HDIM  = 32;
constexpr int ROWS  = BATCH * SEQ;    // 8192
constexpr float NEGV = -9e15f;
constexpr float EPSV = 1e-5f;

typedef __attribute__((ext_vector_type(8))) short short8;
typedef __attribute__((ext_vector_type(4))) float f32x4;

static __device__ __forceinline__ ushort f2bf(float f) {
    unsigned x = __float_as_uint(f);
    unsigned r = (x + 0x7fffu + ((x >> 16) & 1u)) >> 16;   // RNE
    return (ushort)r;
}

// ---------------- generic fp32 -> bf16 cast (n multiple of 4) ----------------
__global__ __launch_bounds__(256) void cast_k(const float* __restrict__ in,
                                              ushort* __restrict__ out, int n4)
{
    int idx = blockIdx.x * 256 + threadIdx.x;
    if (idx >= n4) return;
    float4 v = *(const float4*)&in[(size_t)idx * 4];
    ushort4 o; o.x = f2bf(v.x); o.y = f2bf(v.y); o.z = f2bf(v.z); o.w = f2bf(v.w);
    *(ushort4*)&out[(size_t)idx * 4] = o;
}

// ---------------- transpose-cast: Out[b][c][r] = bf16(In[b][r][c]) ----------------
__global__ __launch_bounds__(256) void tcast_k(const float* __restrict__ In,
                                               ushort* __restrict__ Out,
                                               int R, int C)
{
    __shared__ float Ts[32][33];
    const size_t zo = (size_t)blockIdx.z * R * C;
    const int r0 = blockIdx.y * 32, c0 = blockIdx.x * 32;
    const int t = threadIdx.x;
    const int lr = t >> 3, lc4 = (t & 7) * 4;
    float4 v = *(const float4*)&In[zo + (size_t)(r0 + lr) * C + c0 + lc4];
    Ts[lr][lc4] = v.x; Ts[lr][lc4 + 1] = v.y; Ts[lr][lc4 + 2] = v.z; Ts[lr][lc4 + 3] = v.w;
    __syncthreads();
    const int oc = t >> 3, or4 = (t & 7) * 4;   // output row = c index
    ushort4 o;
    o.x = f2bf(Ts[or4 + 0][oc]); o.y = f2bf(Ts[or4 + 1][oc]);
    o.z = f2bf(Ts[or4 + 2][oc]); o.w = f2bf(Ts[or4 + 3][oc]);
    *(ushort4*)&Out[zo + (size_t)(c0 + oc) * R + r0 + or4] = o;
}

// ---------------- bf16 MFMA GEMM: C = act(A @ B^T + bias) ----------------
// A: (M,K) bf16 row-major. B: (N,K) bf16 row-major. K % 32 == 0, tiles 128x128.
// EP: 0 = plain->f32, 1 = +bias->f32, 2 = +bias,relu->bf16, 3 = elu->f32
template<int EP>
__global__ __launch_bounds__(256) void gemm_bf(const ushort* __restrict__ A,
                                               const ushort* __restrict__ B,
                                               const float* __restrict__ bias,
                                               float* __restrict__ Cf,
                                               ushort* __restrict__ Cb,
                                               int M, int N, int K,
                                               long long sA, long long sB, long long sC)
{
    __shared__ ushort As[128][40];   // pad->stride 80B: frag reads <=2-way
    __shared__ ushort Bs[128][40];
    A += (size_t)blockIdx.z * sA;
    B += (size_t)blockIdx.z * sB;

    const int t  = threadIdx.x;
    const int m0 = blockIdx.y * 128, n0 = blockIdx.x * 128;
    const int lr = t >> 1, lc = (t & 1) * 16;          // staging row / k-chunk
    const int lane = t & 63, lo = lane & 15, hi = lane >> 4;
    const int w = t >> 6;
    const int wr = (w >> 1) * 64, wc = (w & 1) * 64;   // wave tile origin

    f32x4 acc[4][4];
    f32x4 zero = {0.f, 0.f, 0.f, 0.f};
    #pragma unroll
    for (int i = 0; i < 4; i++)
        #pragma unroll
        for (int j = 0; j < 4; j++) acc[i][j] = zero;

    const ushort* Ap = A + (size_t)(m0 + lr) * K + lc;
    const ushort* Bp = B + (size_t)(n0 + lr) * K + lc;

    for (int k0 = 0; k0 < K; k0 += 32) {
        short8 a0 = *(const short8*)(Ap + k0);
        short8 a1 = *(const short8*)(Ap + k0 + 8);
        short8 b0 = *(const short8*)(Bp + k0);
        short8 b1 = *(const short8*)(Bp + k0 + 8);
        __syncthreads();
        *(short8*)&As[lr][lc]     = a0;
        *(short8*)&As[lr][lc + 8] = a1;
        *(short8*)&Bs[lr][lc]     = b0;
        *(short8*)&Bs[lr][lc + 8] = b1;
        __syncthreads();
        short8 afr[4], bfr[4];
        #pragma unroll
        for (int i = 0; i < 4; i++) afr[i] = *(const short8*)&As[wr + i*16 + lo][hi * 8];
        #pragma unroll
        for (int j = 0; j < 4; j++) bfr[j] = *(const short8*)&Bs[wc + j*16 + lo][hi * 8];
        #pragma unroll
        for (int i = 0; i < 4; i++)
            #pragma unroll
            for (int j = 0; j < 4; j++)
                acc[i][j] = __builtin_amdgcn_mfma_f32_16x16x32_bf16(afr[i], bfr[j], acc[i][j], 0, 0, 0);
    }

    // C/D layout: D[row=(hi*4+r)][col=lo] within each 16x16 fragment (m89-verified)
    if (EP == 2) Cb += (size_t)blockIdx.z * sC;
    else         Cf += (size_t)blockIdx.z * sC;
    #pragma unroll
    for (int j = 0; j < 4; j++) {
        const int col = n0 + wc + j * 16 + lo;
        float bj = (EP == 1 || EP == 2) ? bias[col] : 0.f;
        #pragma unroll
        for (int i = 0; i < 4; i++) {
            const int rbase = m0 + wr + i * 16 + hi * 4;
            #pragma unroll
            for (int r = 0; r < 4; r++) {
                float v = acc[i][j][r] + bj;
                if (EP == 3) v = v > 0.f ? v : expm1f(v);
                if (EP == 2) {
                    v = fmaxf(v, 0.f);
                    Cb[(size_t)(rbase + r) * N + col] = f2bf(v);
                } else {
                    Cf[(size_t)(rbase + r) * N + col] = v;
                }
            }
        }
    }
}

// ---------------- LayerNorm(a + r) * g + b (+ optional bf16 copy) ----------------
template<bool WB>
__global__ __launch_bounds__(64) void ln_k(const float* __restrict__ a,
                                           const float* __restrict__ r,
                                           const float* __restrict__ g,
                                           const float* __restrict__ be,
                                           float* __restrict__ o,
                                           ushort* __restrict__ ob)
{
    size_t row = blockIdx.x;
    int t = threadIdx.x;
    const float* pa = a + row * DM;
    const float* pr = r + row * DM;
    float v[4]; float s = 0.f;
    #pragma unroll
    for (int i = 0; i < 4; i++) { v[i] = pa[t + 64*i] + pr[t + 64*i]; s += v[i]; }
    #pragma unroll
    for (int off = 32; off; off >>= 1) s += __shfl_xor(s, off, 64);
    float mu = s * (1.0f / DM);
    float q = 0.f;
    #pragma unroll
    for (int i = 0; i < 4; i++) { float d = v[i] - mu; q += d * d; }
    #pragma unroll
    for (int off = 32; off; off >>= 1) q += __shfl_xor(q, off, 64);
    float rs = rsqrtf(q * (1.0f / DM) + EPSV);
    #pragma unroll
    for (int i = 0; i < 4; i++) {
        int c = t + 64*i;
        float out = (v[i] - mu) * rs * g[c] + be[c];
        o[row * DM + c] = out;
        if (WB) ob[row * DM + c] = f2bf(out);
    }
}

// ---------------- f1 = Wh@a1, f2 = Wh@a2 ----------------
__global__ __launch_bounds__(64) void f12_k(const float* __restrict__ Wh,
                                            const float* __restrict__ a_gat,
                                            float* __restrict__ f1,
                                            float* __restrict__ f2)
{
    size_t row = blockIdx.x;
    int t = threadIdx.x;
    float s1 = 0.f, s2 = 0.f;
    #pragma unroll
    for (int i = 0; i < 4; i++) {
        float w = Wh[row * DM + t + 64*i];
        s1 = fmaf(w, a_gat[t + 64*i], s1);
        s2 = fmaf(w, a_gat[DM + t + 64*i], s2);
    }
    #pragma unroll
    for (int off = 32; off; off >>= 1) {
        s1 += __shfl_xor(s1, off, 64);
        s2 += __shfl_xor(s2, off, 64);
    }
    if (t == 0) { f1[row] = s1; f2[row] = s2; }
}

// ---------------- GAT masked softmax -> normalized P (bf16) ----------------
__global__ __launch_bounds__(256) void gat_sm_k(const int* __restrict__ adj,
                                                const float* __restrict__ f1,
                                                const float* __restrict__ f2,
                                                ushort* __restrict__ P)
{
    __shared__ float red[8];
    const int i = blockIdx.x, b = i >> 10;
    const int t = threadIdx.x;
    const int4 a4 = *(const int4*)&adj[(size_t)i * SEQ + 4 * t];
    const float4 f4 = *(const float4*)&f2[(size_t)(b << 10) + 4 * t];
    const float f1i = f1[i];
    float e[4];
    e[0] = a4.x > 0 ? f1i + f4.x : NEGV;
    e[1] = a4.y > 0 ? f1i + f4.y : NEGV;
    e[2] = a4.z > 0 ? f1i + f4.z : NEGV;
    e[3] = a4.w > 0 ? f1i + f4.w : NEGV;
    float mx = fmaxf(fmaxf(e[0], e[1]), fmaxf(e[2], e[3]));
    #pragma unroll
    for (int off = 32; off; off >>= 1) mx = fmaxf(mx, __shfl_xor(mx, off, 64));
    if ((t & 63) == 0) red[t >> 6] = mx;
    __syncthreads();
    mx = fmaxf(fmaxf(red[0], red[1]), fmaxf(red[2], red[3]));
    float s = 0.f;
    #pragma unroll
    for (int u = 0; u < 4; u++) { e[u] = __expf(e[u] - mx); s += e[u]; }
    #pragma unroll
    for (int off = 32; off; off >>= 1) s += __shfl_xor(s, off, 64);
    if ((t & 63) == 0) red[4 + (t >> 6)] = s;
    __syncthreads();
    float inv = 1.0f / (red[4] + red[5] + red[6] + red[7]);
    ushort4 o;
    o.x = f2bf(e[0] * inv); o.y = f2bf(e[1] * inv);
    o.z = f2bf(e[2] * inv); o.w = f2bf(e[3] * inv);
    *(ushort4*)&P[(size_t)i * SEQ + 4 * t] = o;
}

// ---------------- MHA: flash-style fp32, 64 q-rows per block, bf16 ctx out ----------------
__global__ __launch_bounds__(256) void mha_k(const float* __restrict__ qkv,
                                             ushort* __restrict__ ctxb)
{
    __shared__ float Qs[64][36];
    __shared__ float Kt[32][68];
    __shared__ float Vs[64][36];
    __shared__ float Ps[64][68];

    const int blk = blockIdx.x;
    const int qt = blk & 15;
    const int h  = (blk >> 4) & 7;
    const int b  = blk >> 7;
    const int i0 = qt << 6;
    const int t  = threadIdx.x;
    const int g  = t >> 4;
    const int c  = t & 15;
    const size_t base = (size_t)b * SEQ * 768;

    {
        const int row = t >> 2, cb = (t & 3) << 3;
        const float* src = qkv + base + (size_t)(i0 + row) * 768 + h * HDIM + cb;
        const float s = 0.17677669529663687f;
        float4 v0 = *(const float4*)src, v1 = *(const float4*)(src + 4);
        v0.x*=s; v0.y*=s; v0.z*=s; v0.w*=s; v1.x*=s; v1.y*=s; v1.z*=s; v1.w*=s;
        *(float4*)&Qs[row][cb]     = v0;
        *(float4*)&Qs[row][cb + 4] = v1;
    }

    float m_run[4], l_run[4], Oa[4][2];
    #pragma unroll
    for (int i = 0; i < 4; i++) { m_run[i] = -3.4e38f; l_run[i] = 0.f; Oa[i][0] = 0.f; Oa[i][1] = 0.f; }

    for (int j0 = 0; j0 < SEQ; j0 += 64) {
        __syncthreads();
        {
            const int row = t >> 2, cb = (t & 3) << 3;
            const float* kp = qkv + base + (size_t)(j0 + row) * 768 + 256 + h * HDIM + cb;
            float4 k0 = *(const float4*)kp, k1 = *(const float4*)(kp + 4);
            Kt[cb+0][row] = k0.x; Kt[cb+1][row] = k0.y; Kt[cb+2][row] = k0.z; Kt[cb+3][row] = k0.w;
            Kt[cb+4][row] = k1.x; Kt[cb+5][row] = k1.y; Kt[cb+6][row] = k1.z; Kt[cb+7][row] = k1.w;
            const float* vp = qkv + base + (size_t)(j0 + row) * 768 + 512 + h * HDIM + cb;
            *(float4*)&Vs[row][cb]     = *(const float4*)vp;
            *(float4*)&Vs[row][cb + 4] = *(const float4*)(vp + 4);
        }
        __syncthreads();

        float S[4][4] = {};
        #pragma unroll
        for (int k0 = 0; k0 < HDIM; k0 += 4) {
            float4 qv[4];
            #pragma unroll
            for (int i = 0; i < 4; i++) qv[i] = *(const float4*)&Qs[4*g + i][k0];
            #pragma unroll
            for (int kk = 0; kk < 4; kk++) {
                float kv[4];
                #pragma unroll
                for (int j = 0; j < 4; j++) kv[j] = Kt[k0 + kk][c + 16*j];
                #pragma unroll
                for (int i = 0; i < 4; i++) {
                    float qe = (&qv[i].x)[kk];
                    #pragma unroll
                    for (int j = 0; j < 4; j++) S[i][j] = fmaf(qe, kv[j], S[i][j]);
                }
            }
        }

        #pragma unroll
        for (int i = 0; i < 4; i++) {
            float tmax = fmaxf(fmaxf(S[i][0], S[i][1]), fmaxf(S[i][2], S[i][3]));
            #pragma unroll
            for (int off = 8; off; off >>= 1) tmax = fmaxf(tmax, __shfl_xor(tmax, off, 16));
            float mnew = fmaxf(m_run[i], tmax);
            float sc = __expf(m_run[i] - mnew);
            m_run[i] = mnew;
            float rs = 0.f;
            #pragma unroll
            for (int j = 0; j < 4; j++) { S[i][j] = __expf(S[i][j] - mnew); rs += S[i][j]; }
            #pragma unroll
            for (int off = 8; off; off >>= 1) rs += __shfl_xor(rs, off, 16);
            l_run[i] = l_run[i] * sc + rs;
            Oa[i][0] *= sc; Oa[i][1] *= sc;
            #pragma unroll
            for (int j = 0; j < 4; j++) Ps[4*g + i][c + 16*j] = S[i][j];
        }
        __syncthreads();

        #pragma unroll
        for (int jj0 = 0; jj0 < 64; jj0 += 4) {
            float4 pv[4];
            #pragma unroll
            for (int i = 0; i < 4; i++) pv[i] = *(const float4*)&Ps[4*g + i][jj0];
            #pragma unroll
            for (int q = 0; q < 4; q++) {
                float2 vv = *(const float2*)&Vs[jj0 + q][2*c];
                #pragma unroll
                for (int i = 0; i < 4; i++) {
                    float pe = (&pv[i].x)[q];
                    Oa[i][0] = fmaf(pe, vv.x, Oa[i][0]);
                    Oa[i][1] = fmaf(pe, vv.y, Oa[i][1]);
                }
            }
        }
    }

    #pragma unroll
    for (int i = 0; i < 4; i++) {
        float inv = 1.0f / l_run[i];
        size_t row = (size_t)(b * SEQ) + i0 + 4*g + i;
        ushort2 o; o.x = f2bf(Oa[i][0] * inv); o.y = f2bf(Oa[i][1] * inv);
        *(ushort2*)&ctxb[row * DM + h * HDIM + 2*c] = o;
    }
}

extern "C" void kernel_launch(void* const* d_in, const int* in_sizes, int n_in,
                              void* d_out, int out_size, void* d_ws, size_t ws_size,
                              hipStream_t stream)
{
    const float* src        = (const float*)d_in[0];
    const int*   adj        = (const int*)  d_in[1];
    const float* W_gat      = (const float*)d_in[2];
    const float* a_gat      = (const float*)d_in[3];
    const float* in_proj_w  = (const float*)d_in[4];
    const float* in_proj_b  = (const float*)d_in[5];
    const float* out_proj_w = (const float*)d_in[6];
    const float* out_proj_b = (const float*)d_in[7];
    const float* lin1_w     = (const float*)d_in[8];
    const float* lin1_b     = (const float*)d_in[9];
    const float* lin2_w     = (const float*)d_in[10];
    const float* lin2_b     = (const float*)d_in[11];
    const float* ln1_g      = (const float*)d_in[12];
    const float* ln1_b_     = (const float*)d_in[13];
    const float* ln2_g      = (const float*)d_in[14];
    const float* ln2_b_     = (const float*)d_in[15];
    const float* ln3_g      = (const float*)d_in[16];
    const float* ln3_b_     = (const float*)d_in[17];

    char* base = (char*)d_ws;
    const size_t MB = 1024 * 1024;
    float*  Wh    = (float*) (base + 0 * MB);    // 8 MB
    float*  tmp   = (float*) (base + 8 * MB);    // 8 MB
    float*  x     = (float*) (base + 16 * MB);   // 8 MB
    float*  y     = (float*) (base + 24 * MB);   // 8 MB
    // BIG shared region [32MB, 64MB): P_bf -> qkv -> ff1_bf (strictly sequential lifetimes)
    ushort* P_bf  = (ushort*)(base + 32 * MB);   // 16 MB
    float*  qkv   = (float*) (base + 32 * MB);   // 24 MB
    ushort* ff1b  = (ushort*)(base + 32 * MB);   // 32 MB
    ushort* srcb  = (ushort*)(base + 64 * MB);   // 4 MB
    ushort* WhTb  = (ushort*)(base + 68 * MB);   // 4 MB
    ushort* xb    = (ushort*)(base + 72 * MB);   // 4 MB
    ushort* yb    = (ushort*)(base + 76 * MB);   // 4 MB
    ushort* ctxb  = (ushort*)(base + 80 * MB);   // 4 MB
    float*  f1    = (float*) (base + 84 * MB);   // 32 KB
    float*  f2    = f1 + ROWS;
    ushort* wgTb  = (ushort*)(base + 85 * MB);   // 128 KB
    ushort* ipwb  = wgTb + 65536;                // 384 KB
    ushort* opwb  = ipwb + 196608;               // 128 KB
    ushort* l1wb  = opwb + 65536;                // 1 MB
    ushort* l2wb  = l1wb + 524288;               // 1 MB

    dim3 b256(256), b64(64);

    // --- casts ---
    cast_k<<<2097152/4/256, b256, 0, stream>>>(src, srcb, 2097152/4);
    cast_k<<<196608/4/256,  b256, 0, stream>>>(in_proj_w, ipwb, 196608/4);
    cast_k<<<65536/4/256,   b256, 0, stream>>>(out_proj_w, opwb, 65536/4);
    cast_k<<<524288/4/256,  b256, 0, stream>>>(lin1_w, l1wb, 524288/4);
    cast_k<<<524288/4/256,  b256, 0, stream>>>(lin2_w, l2wb, 524288/4);
    tcast_k<<<dim3(8, 8, 1), b256, 0, stream>>>(W_gat, wgTb, 256, 256);

    // --- Wh = src @ W_gat (fp32 out) ---
    gemm_bf<0><<<dim3(2, 64, 1), b256, 0, stream>>>(srcb, wgTb, nullptr, Wh, nullptr,
                                                    ROWS, DM, DM, 0, 0, 0);
    f12_k<<<ROWS, b64, 0, stream>>>(Wh, a_gat, f1, f2);
    tcast_k<<<dim3(8, 32, 8), b256, 0, stream>>>(Wh, WhTb, SEQ, DM);   // WhT[b][n][k]

    // --- GAT: softmax probs -> P_bf; graph_out = elu(P @ Wh) ---
    gat_sm_k<<<ROWS, b256, 0, stream>>>(adj, f1, f2, P_bf);
    gemm_bf<3><<<dim3(2, 8, 8), b256, 0, stream>>>(P_bf, WhTb, nullptr, tmp, nullptr,
                                                   SEQ, DM, SEQ,
                                                   (long long)SEQ*SEQ, (long long)DM*SEQ, (long long)SEQ*DM);
    ln_k<true><<<ROWS, b64, 0, stream>>>(src, tmp, ln1_g, ln1_b_, x, xb);

    // --- MHA ---
    gemm_bf<1><<<dim3(6, 64, 1), b256, 0, stream>>>(xb, ipwb, in_proj_b, qkv, nullptr,
                                                    ROWS, 768, DM, 0, 0, 0);
    mha_k<<<BATCH*NH*(SEQ/64), b256, 0, stream>>>(qkv, ctxb);
    gemm_bf<1><<<dim3(2, 64, 1), b256, 0, stream>>>(ctxb, opwb, out_proj_b, tmp, nullptr,
                                                    ROWS, DM, DM, 0, 0, 0);
    ln_k<true><<<ROWS, b64, 0, stream>>>(x, tmp, ln2_g, ln2_b_, y, yb);

    // --- FFN ---
    gemm_bf<2><<<dim3(16, 64, 1), b256, 0, stream>>>(yb, l1wb, lin1_b, nullptr, ff1b,
                                                     ROWS, DF, DM, 0, 0, 0);
    gemm_bf<1><<<dim3(2, 64, 1), b256, 0, stream>>>(ff1b, l2wb, lin2_b, tmp, nullptr,
                                                    ROWS, DM, DF, 0, 0, 0);
    ln_k<false><<<ROWS, b64, 0, stream>>>(y, tmp, ln3_g, ln3_b_, (float*)d_out, nullptr);
}

// Round 5
// 246.940 us; speedup vs baseline: 7.9733x; 1.5054x over previous
//
#include <hip/hip_runtime.h>
#include <math.h>

constexpr int BATCH = 8;
constexpr int SEQ   = 1024;
constexpr int DM    = 256;
constexpr int DF    = 2048;
constexpr int NH    = 8;
constexpr int HDIM  = 32;
constexpr int ROWS  = BATCH * SEQ;    // 8192
constexpr float NEGV = -9e15f;
constexpr float EPSV = 1e-5f;

typedef __attribute__((ext_vector_type(8))) short short8;
typedef __attribute__((ext_vector_type(4))) float f32x4;

static __device__ __forceinline__ ushort f2bf(float f) {
    unsigned x = __float_as_uint(f);
    unsigned r = (x + 0x7fffu + ((x >> 16) & 1u)) >> 16;   // RNE
    return (ushort)r;
}

// ---------------- generic fp32 -> bf16 cast (n multiple of 4) ----------------
__global__ __launch_bounds__(256) void cast_k(const float* __restrict__ in,
                                              ushort* __restrict__ out, int n4)
{
    int idx = blockIdx.x * 256 + threadIdx.x;
    if (idx >= n4) return;
    float4 v = *(const float4*)&in[(size_t)idx * 4];
    ushort4 o; o.x = f2bf(v.x); o.y = f2bf(v.y); o.z = f2bf(v.z); o.w = f2bf(v.w);
    *(ushort4*)&out[(size_t)idx * 4] = o;
}

// ---------------- transpose-cast: Out[b][c][r] = bf16(In[b][r][c]) ----------------
__global__ __launch_bounds__(256) void tcast_k(const float* __restrict__ In,
                                               ushort* __restrict__ Out,
                                               int R, int C)
{
    __shared__ float Ts[32][33];
    const size_t zo = (size_t)blockIdx.z * R * C;
    const int r0 = blockIdx.y * 32, c0 = blockIdx.x * 32;
    const int t = threadIdx.x;
    const int lr = t >> 3, lc4 = (t & 7) * 4;
    float4 v = *(const float4*)&In[zo + (size_t)(r0 + lr) * C + c0 + lc4];
    Ts[lr][lc4] = v.x; Ts[lr][lc4 + 1] = v.y; Ts[lr][lc4 + 2] = v.z; Ts[lr][lc4 + 3] = v.w;
    __syncthreads();
    const int oc = t >> 3, or4 = (t & 7) * 4;
    ushort4 o;
    o.x = f2bf(Ts[or4 + 0][oc]); o.y = f2bf(Ts[or4 + 1][oc]);
    o.z = f2bf(Ts[or4 + 2][oc]); o.w = f2bf(Ts[or4 + 3][oc]);
    *(ushort4*)&Out[zo + (size_t)(c0 + oc) * R + r0 + or4] = o;
}

// ---------------- bf16 MFMA GEMM: C = act(A @ B^T + bias) ----------------
// EP: 0 plain->f32, 1 +bias->f32, 2 +bias,relu->bf16, 3 elu->f32, 4 +bias->bf16
template<int EP>
__global__ __launch_bounds__(256) void gemm_bf(const ushort* __restrict__ A,
                                               const ushort* __restrict__ B,
                                               const float* __restrict__ bias,
                                               float* __restrict__ Cf,
                                               ushort* __restrict__ Cb,
                                               int M, int N, int K,
                                               long long sA, long long sB, long long sC)
{
    __shared__ ushort As[128][40];
    __shared__ ushort Bs[128][40];
    A += (size_t)blockIdx.z * sA;
    B += (size_t)blockIdx.z * sB;

    const int t  = threadIdx.x;
    const int m0 = blockIdx.y * 128, n0 = blockIdx.x * 128;
    const int lr = t >> 1, lc = (t & 1) * 16;
    const int lane = t & 63, lo = lane & 15, hi = lane >> 4;
    const int w = t >> 6;
    const int wr = (w >> 1) * 64, wc = (w & 1) * 64;

    f32x4 acc[4][4];
    f32x4 zero = {0.f, 0.f, 0.f, 0.f};
    #pragma unroll
    for (int i = 0; i < 4; i++)
        #pragma unroll
        for (int j = 0; j < 4; j++) acc[i][j] = zero;

    const ushort* Ap = A + (size_t)(m0 + lr) * K + lc;
    const ushort* Bp = B + (size_t)(n0 + lr) * K + lc;

    for (int k0 = 0; k0 < K; k0 += 32) {
        short8 a0 = *(const short8*)(Ap + k0);
        short8 a1 = *(const short8*)(Ap + k0 + 8);
        short8 b0 = *(const short8*)(Bp + k0);
        short8 b1 = *(const short8*)(Bp + k0 + 8);
        __syncthreads();
        *(short8*)&As[lr][lc]     = a0;
        *(short8*)&As[lr][lc + 8] = a1;
        *(short8*)&Bs[lr][lc]     = b0;
        *(short8*)&Bs[lr][lc + 8] = b1;
        __syncthreads();
        short8 afr[4], bfr[4];
        #pragma unroll
        for (int i = 0; i < 4; i++) afr[i] = *(const short8*)&As[wr + i*16 + lo][hi * 8];
        #pragma unroll
        for (int j = 0; j < 4; j++) bfr[j] = *(const short8*)&Bs[wc + j*16 + lo][hi * 8];
        #pragma unroll
        for (int i = 0; i < 4; i++)
            #pragma unroll
            for (int j = 0; j < 4; j++)
                acc[i][j] = __builtin_amdgcn_mfma_f32_16x16x32_bf16(afr[i], bfr[j], acc[i][j], 0, 0, 0);
    }

    if (EP == 2 || EP == 4) Cb += (size_t)blockIdx.z * sC;
    else                    Cf += (size_t)blockIdx.z * sC;
    #pragma unroll
    for (int j = 0; j < 4; j++) {
        const int col = n0 + wc + j * 16 + lo;
        float bj = (EP == 1 || EP == 2 || EP == 4) ? bias[col] : 0.f;
        #pragma unroll
        for (int i = 0; i < 4; i++) {
            const int rbase = m0 + wr + i * 16 + hi * 4;
            #pragma unroll
            for (int r = 0; r < 4; r++) {
                float v = acc[i][j][r] + bj;
                if (EP == 3) v = v > 0.f ? v : expm1f(v);
                if (EP == 2) v = fmaxf(v, 0.f);
                if (EP == 2 || EP == 4) Cb[(size_t)(rbase + r) * N + col] = f2bf(v);
                else                    Cf[(size_t)(rbase + r) * N + col] = v;
            }
        }
    }
}

// ---------------- LayerNorm(a + r) * g + b (+ optional bf16 copy) ----------------
template<bool WB>
__global__ __launch_bounds__(64) void ln_k(const float* __restrict__ a,
                                           const float* __restrict__ r,
                                           const float* __restrict__ g,
                                           const float* __restrict__ be,
                                           float* __restrict__ o,
                                           ushort* __restrict__ ob)
{
    size_t row = blockIdx.x;
    int t = threadIdx.x;
    const float* pa = a + row * DM;
    const float* pr = r + row * DM;
    float v[4]; float s = 0.f;
    #pragma unroll
    for (int i = 0; i < 4; i++) { v[i] = pa[t + 64*i] + pr[t + 64*i]; s += v[i]; }
    #pragma unroll
    for (int off = 32; off; off >>= 1) s += __shfl_xor(s, off, 64);
    float mu = s * (1.0f / DM);
    float q = 0.f;
    #pragma unroll
    for (int i = 0; i < 4; i++) { float d = v[i] - mu; q += d * d; }
    #pragma unroll
    for (int off = 32; off; off >>= 1) q += __shfl_xor(q, off, 64);
    float rs = rsqrtf(q * (1.0f / DM) + EPSV);
    #pragma unroll
    for (int i = 0; i < 4; i++) {
        int c = t + 64*i;
        float out = (v[i] - mu) * rs * g[c] + be[c];
        o[row * DM + c] = out;
        if (WB) ob[row * DM + c] = f2bf(out);
    }
}

// ---------------- f1 = Wh@a1, f2 = Wh@a2 ----------------
__global__ __launch_bounds__(64) void f12_k(const float* __restrict__ Wh,
                                            const float* __restrict__ a_gat,
                                            float* __restrict__ f1,
                                            float* __restrict__ f2)
{
    size_t row = blockIdx.x;
    int t = threadIdx.x;
    float s1 = 0.f, s2 = 0.f;
    #pragma unroll
    for (int i = 0; i < 4; i++) {
        float w = Wh[row * DM + t + 64*i];
        s1 = fmaf(w, a_gat[t + 64*i], s1);
        s2 = fmaf(w, a_gat[DM + t + 64*i], s2);
    }
    #pragma unroll
    for (int off = 32; off; off >>= 1) {
        s1 += __shfl_xor(s1, off, 64);
        s2 += __shfl_xor(s2, off, 64);
    }
    if (t == 0) { f1[row] = s1; f2[row] = s2; }
}

// ---------------- GAT masked softmax -> normalized P (bf16) ----------------
__global__ __launch_bounds__(256) void gat_sm_k(const int* __restrict__ adj,
                                                const float* __restrict__ f1,
                                                const float* __restrict__ f2,
                                                ushort* __restrict__ P)
{
    __shared__ float red[8];
    const int i = blockIdx.x, b = i >> 10;
    const int t = threadIdx.x;
    const int4 a4 = *(const int4*)&adj[(size_t)i * SEQ + 4 * t];
    const float4 f4 = *(const float4*)&f2[(size_t)(b << 10) + 4 * t];
    const float f1i = f1[i];
    float e[4];
    e[0] = a4.x > 0 ? f1i + f4.x : NEGV;
    e[1] = a4.y > 0 ? f1i + f4.y : NEGV;
    e[2] = a4.z > 0 ? f1i + f4.z : NEGV;
    e[3] = a4.w > 0 ? f1i + f4.w : NEGV;
    float mx = fmaxf(fmaxf(e[0], e[1]), fmaxf(e[2], e[3]));
    #pragma unroll
    for (int off = 32; off; off >>= 1) mx = fmaxf(mx, __shfl_xor(mx, off, 64));
    if ((t & 63) == 0) red[t >> 6] = mx;
    __syncthreads();
    mx = fmaxf(fmaxf(red[0], red[1]), fmaxf(red[2], red[3]));
    float s = 0.f;
    #pragma unroll
    for (int u = 0; u < 4; u++) { e[u] = __expf(e[u] - mx); s += e[u]; }
    #pragma unroll
    for (int off = 32; off; off >>= 1) s += __shfl_xor(s, off, 64);
    if ((t & 63) == 0) red[4 + (t >> 6)] = s;
    __syncthreads();
    float inv = 1.0f / (red[4] + red[5] + red[6] + red[7]);
    ushort4 o;
    o.x = f2bf(e[0] * inv); o.y = f2bf(e[1] * inv);
    o.z = f2bf(e[2] * inv); o.w = f2bf(e[3] * inv);
    *(ushort4*)&P[(size_t)i * SEQ + 4 * t] = o;
}

// ---------------- MHA: bf16 MFMA flash, 64 q-rows per block, 4 waves ----------------
// Vt keeps the skewed flat layout (collision-free; conflict-free scatter writes).
// Ps is a plain padded 2-D array: the round-4 skewed ps_idx overflowed its row
// stride (skew 24 + col 63 = 87 > 72) and aliased rows 15/16, 31/32, 47/48
// across waves -> race. Stride 72 ushorts = 144 B keeps short8 reads 16B-aligned.
__device__ __forceinline__ int vt_idx(int d, int kv) { return d * 72 + ((d >> 3) & 3) * 16 + kv; }

__global__ __launch_bounds__(256) void mha_k(const ushort* __restrict__ qkv,
                                             ushort* __restrict__ ctxb)
{
    __shared__ ushort Qs[64][40];
    __shared__ ushort Ks[64][40];
    __shared__ ushort Vt[32 * 72 + 3 * 16 + 8];
    __shared__ ushort Ps[64][72];

    const int blk = blockIdx.x;
    const int qt = blk & 15, h = (blk >> 4) & 7, b = blk >> 7;
    const int i0 = qt << 6;
    const int t = threadIdx.x;
    const int w = t >> 6, lane = t & 63, lo = lane & 15, hi = lane >> 4;
    const size_t base = (size_t)b * SEQ * 768;
    const float scale = 0.17677669529663687f;   // 1/sqrt(32)

    {   // stage Q tile (64 x 32 bf16)
        const int row = t >> 2, cb = (t & 3) << 3;
        *(short8*)&Qs[row][cb] = *(const short8*)(qkv + base + (size_t)(i0 + row) * 768 + h * HDIM + cb);
    }

    float m_run[4], l_run[4];
    f32x4 O0 = {0.f, 0.f, 0.f, 0.f}, O1 = {0.f, 0.f, 0.f, 0.f};
    #pragma unroll
    for (int r = 0; r < 4; r++) { m_run[r] = -3.4e38f; l_run[r] = 0.f; }
    const f32x4 zero = {0.f, 0.f, 0.f, 0.f};

    for (int j0 = 0; j0 < SEQ; j0 += 64) {
        __syncthreads();
        {   // stage K row-major, V transposed (skewed)
            const int row = t >> 2, cb = (t & 3) << 3;
            const ushort* kp = qkv + base + (size_t)(j0 + row) * 768 + 256 + h * HDIM + cb;
            *(short8*)&Ks[row][cb] = *(const short8*)kp;
            short8 v = *(const short8*)(qkv + base + (size_t)(j0 + row) * 768 + 512 + h * HDIM + cb);
            #pragma unroll
            for (int e = 0; e < 8; e++) Vt[vt_idx(cb + e, row)] = (ushort)v[e];
        }
        __syncthreads();

        // S = Q K^T  (wave w: q rows 16w..16w+15, all 64 kv)
        short8 aQ = *(const short8*)&Qs[16 * w + lo][hi * 8];
        f32x4 S[4];
        #pragma unroll
        for (int jt = 0; jt < 4; jt++) {
            short8 bK = *(const short8*)&Ks[16 * jt + lo][hi * 8];
            S[jt] = __builtin_amdgcn_mfma_f32_16x16x32_bf16(aQ, bK, zero, 0, 0, 0);
        }

        // online softmax; lane owns rows q_local = 16w + hi*4 + r, cols lo+16jt
        #pragma unroll
        for (int r = 0; r < 4; r++) {
            float mx = -3.4e38f;
            #pragma unroll
            for (int jt = 0; jt < 4; jt++) { S[jt][r] *= scale; mx = fmaxf(mx, S[jt][r]); }
            #pragma unroll
            for (int off = 8; off; off >>= 1) mx = fmaxf(mx, __shfl_xor(mx, off, 16));
            float mnew = fmaxf(m_run[r], mx);
            float sc = __expf(m_run[r] - mnew);
            m_run[r] = mnew;
            float rs = 0.f;
            #pragma unroll
            for (int jt = 0; jt < 4; jt++) {
                float p = __expf(S[jt][r] - mnew);
                rs += p;
                Ps[16 * w + hi * 4 + r][lo + 16 * jt] = f2bf(p);
            }
            #pragma unroll
            for (int off = 8; off; off >>= 1) rs += __shfl_xor(rs, off, 16);
            l_run[r] = l_run[r] * sc + rs;
            O0[r] *= sc; O1[r] *= sc;
        }

        // O += P V   (Ps rows 16w..16w+15 are wave-private: no barrier needed)
        #pragma unroll
        for (int kt = 0; kt < 2; kt++) {
            short8 aP  = *(const short8*)&Ps[16 * w + lo][32 * kt + hi * 8];
            short8 bV0 = *(const short8*)&Vt[vt_idx(lo,      32 * kt + hi * 8)];
            short8 bV1 = *(const short8*)&Vt[vt_idx(16 + lo, 32 * kt + hi * 8)];
            O0 = __builtin_amdgcn_mfma_f32_16x16x32_bf16(aP, bV0, O0, 0, 0, 0);
            O1 = __builtin_amdgcn_mfma_f32_16x16x32_bf16(aP, bV1, O1, 0, 0, 0);
        }
    }

    #pragma unroll
    for (int r = 0; r < 4; r++) {
        float inv = 1.0f / l_run[r];
        size_t row = (size_t)b * SEQ + i0 + 16 * w + hi * 4 + r;
        ctxb[row * DM + h * HDIM + lo]      = f2bf(O0[r] * inv);
        ctxb[row * DM + h * HDIM + 16 + lo] = f2bf(O1[r] * inv);
    }
}

extern "C" void kernel_launch(void* const* d_in, const int* in_sizes, int n_in,
                              void* d_out, int out_size, void* d_ws, size_t ws_size,
                              hipStream_t stream)
{
    const float* src        = (const float*)d_in[0];
    const int*   adj        = (const int*)  d_in[1];
    const float* W_gat      = (const float*)d_in[2];
    const float* a_gat      = (const float*)d_in[3];
    const float* in_proj_w  = (const float*)d_in[4];
    const float* in_proj_b  = (const float*)d_in[5];
    const float* out_proj_w = (const float*)d_in[6];
    const float* out_proj_b = (const float*)d_in[7];
    const float* lin1_w     = (const float*)d_in[8];
    const float* lin1_b     = (const float*)d_in[9];
    const float* lin2_w     = (const float*)d_in[10];
    const float* lin2_b     = (const float*)d_in[11];
    const float* ln1_g      = (const float*)d_in[12];
    const float* ln1_b_     = (const float*)d_in[13];
    const float* ln2_g      = (const float*)d_in[14];
    const float* ln2_b_     = (const float*)d_in[15];
    const float* ln3_g      = (const float*)d_in[16];
    const float* ln3_b_     = (const float*)d_in[17];

    char* base = (char*)d_ws;
    const size_t MB = 1024 * 1024;
    float*  Wh    = (float*) (base + 0 * MB);    // 8 MB
    float*  tmp   = (float*) (base + 8 * MB);    // 8 MB
    float*  x     = (float*) (base + 16 * MB);   // 8 MB
    float*  y     = (float*) (base + 24 * MB);   // 8 MB
    // BIG shared region [32MB, 64MB): P_bf -> qkvb -> ff1b (sequential lifetimes)
    ushort* P_bf  = (ushort*)(base + 32 * MB);   // 16 MB
    ushort* qkvb  = (ushort*)(base + 32 * MB);   // 12 MB
    ushort* ff1b  = (ushort*)(base + 32 * MB);   // 32 MB
    ushort* srcb  = (ushort*)(base + 64 * MB);   // 4 MB
    ushort* WhTb  = (ushort*)(base + 68 * MB);   // 4 MB
    ushort* xb    = (ushort*)(base + 72 * MB);   // 4 MB
    ushort* yb    = (ushort*)(base + 76 * MB);   // 4 MB
    ushort* ctxb  = (ushort*)(base + 80 * MB);   // 4 MB
    float*  f1    = (float*) (base + 84 * MB);   // 32 KB
    float*  f2    = f1 + ROWS;
    ushort* wgTb  = (ushort*)(base + 85 * MB);   // 128 KB
    ushort* ipwb  = wgTb + 65536;                // 384 KB
    ushort* opwb  = ipwb + 196608;               // 128 KB
    ushort* l1wb  = opwb + 65536;                // 1 MB
    ushort* l2wb  = l1wb + 524288;               // 1 MB

    dim3 b256(256), b64(64);

    // --- casts ---
    cast_k<<<2097152/4/256, b256, 0, stream>>>(src, srcb, 2097152/4);
    cast_k<<<196608/4/256,  b256, 0, stream>>>(in_proj_w, ipwb, 196608/4);
    cast_k<<<65536/4/256,   b256, 0, stream>>>(out_proj_w, opwb, 65536/4);
    cast_k<<<524288/4/256,  b256, 0, stream>>>(lin1_w, l1wb, 524288/4);
    cast_k<<<524288/4/256,  b256, 0, stream>>>(lin2_w, l2wb, 524288/4);
    tcast_k<<<dim3(8, 8, 1), b256, 0, stream>>>(W_gat, wgTb, 256, 256);

    // --- Wh = src @ W_gat ---
    gemm_bf<0><<<dim3(2, 64, 1), b256, 0, stream>>>(srcb, wgTb, nullptr, Wh, nullptr,
                                                    ROWS, DM, DM, 0, 0, 0);
    f12_k<<<ROWS, b64, 0, stream>>>(Wh, a_gat, f1, f2);
    tcast_k<<<dim3(8, 32, 8), b256, 0, stream>>>(Wh, WhTb, SEQ, DM);

    // --- GAT ---
    gat_sm_k<<<ROWS, b256, 0, stream>>>(adj, f1, f2, P_bf);
    gemm_bf<3><<<dim3(2, 8, 8), b256, 0, stream>>>(P_bf, WhTb, nullptr, tmp, nullptr,
                                                   SEQ, DM, SEQ,
                                                   (long long)SEQ*SEQ, (long long)DM*SEQ, (long long)SEQ*DM);
    ln_k<true><<<ROWS, b64, 0, stream>>>(src, tmp, ln1_g, ln1_b_, x, xb);

    // --- MHA (bf16 qkv -> MFMA flash) ---
    gemm_bf<4><<<dim3(6, 64, 1), b256, 0, stream>>>(xb, ipwb, in_proj_b, nullptr, qkvb,
                                                    ROWS, 768, DM, 0, 0, 0);
    mha_k<<<BATCH*NH*(SEQ/64), b256, 0, stream>>>(qkvb, ctxb);
    gemm_bf<1><<<dim3(2, 64, 1), b256, 0, stream>>>(ctxb, opwb, out_proj_b, tmp, nullptr,
                                                    ROWS, DM, DM, 0, 0, 0);
    ln_k<true><<<ROWS, b64, 0, stream>>>(x, tmp, ln2_g, ln2_b_, y, yb);

    // --- FFN ---
    gemm_bf<2><<<dim3(16, 64, 1), b256, 0, stream>>>(yb, l1wb, lin1_b, nullptr, ff1b,
                                                     ROWS, DF, DM, 0, 0, 0);
    gemm_bf<1><<<dim3(2, 64, 1), b256, 0, stream>>>(ff1b, l2wb, lin2_b, tmp, nullptr,
                                                    ROWS, DM, DF, 0, 0, 0);
    ln_k<false><<<ROWS, b64, 0, stream>>>(y, tmp, ln3_g, ln3_b_, (float*)d_out, nullptr);
}

// Round 6
// 236.431 us; speedup vs baseline: 8.3277x; 1.0444x over previous
//
#include <hip/hip_runtime.h>
#include <math.h>

constexpr int BATCH = 8;
constexpr int SEQ   = 1024;
constexpr int DM    = 256;
constexpr int DF    = 2048;
constexpr int NH    = 8;
constexpr int HDIM  = 32;
constexpr int ROWS  = BATCH * SEQ;    // 8192
constexpr float NEGV = -9e15f;
constexpr float EPSV = 1e-5f;
// 1/sqrt(32) * log2(e): Q pre-scale so softmax runs in exp2 domain
constexpr float QSCALE = 0.2550351822f;

typedef __attribute__((ext_vector_type(8))) short short8;
typedef __attribute__((ext_vector_type(4))) float f32x4;

static __device__ __forceinline__ ushort f2bf(float f) {
    unsigned x = __float_as_uint(f);
    unsigned r = (x + 0x7fffu + ((x >> 16) & 1u)) >> 16;   // RNE
    return (ushort)r;
}
static __device__ __forceinline__ unsigned cvt_pk_bf16(float lo, float hi) {
    unsigned r;
    asm volatile("v_cvt_pk_bf16_f32 %0, %1, %2" : "=v"(r) : "v"(lo), "v"(hi));
    return r;
}

// ---------------- fused fp32 -> bf16 cast of 5 regions ----------------
struct CastArgs {
    const float* in[5];
    ushort* out[5];
    int n4[5];            // float4 count per region
};
__global__ __launch_bounds__(256) void castall_k(CastArgs a)
{
    int idx = blockIdx.x * 256 + threadIdx.x;
    #pragma unroll
    for (int r = 0; r < 5; r++) {
        if (idx < a.n4[r]) {
            float4 v = *(const float4*)&a.in[r][(size_t)idx * 4];
            ushort4 o; o.x = f2bf(v.x); o.y = f2bf(v.y); o.z = f2bf(v.z); o.w = f2bf(v.w);
            *(ushort4*)&a.out[r][(size_t)idx * 4] = o;
            return;
        }
        idx -= a.n4[r];
    }
}

// ---------------- transpose-cast: Out[c][r] = bf16(In[r][c]) ----------------
__global__ __launch_bounds__(256) void tcast_k(const float* __restrict__ In,
                                               ushort* __restrict__ Out,
                                               int R, int C)
{
    __shared__ float Ts[32][33];
    const int r0 = blockIdx.y * 32, c0 = blockIdx.x * 32;
    const int t = threadIdx.x;
    const int lr = t >> 3, lc4 = (t & 7) * 4;
    float4 v = *(const float4*)&In[(size_t)(r0 + lr) * C + c0 + lc4];
    Ts[lr][lc4] = v.x; Ts[lr][lc4 + 1] = v.y; Ts[lr][lc4 + 2] = v.z; Ts[lr][lc4 + 3] = v.w;
    __syncthreads();
    const int oc = t >> 3, or4 = (t & 7) * 4;
    ushort4 o;
    o.x = f2bf(Ts[or4 + 0][oc]); o.y = f2bf(Ts[or4 + 1][oc]);
    o.z = f2bf(Ts[or4 + 2][oc]); o.w = f2bf(Ts[or4 + 3][oc]);
    *(ushort4*)&Out[(size_t)(c0 + oc) * R + r0 + or4] = o;
}

// ---------------- w1 = W_gat @ a1, w2 = W_gat @ a2 (256-vectors) ----------------
__global__ __launch_bounds__(256) void w12_k(const float* __restrict__ W_gat,
                                             const float* __restrict__ a_gat,
                                             float* __restrict__ w1,
                                             float* __restrict__ w2)
{
    const int t = threadIdx.x;
    const int k = blockIdx.x * 4 + (t >> 6);
    const int l = t & 63;
    float4 wv = *(const float4*)&W_gat[(size_t)k * DM + 4 * l];
    float4 a1 = *(const float4*)&a_gat[4 * l];
    float4 a2 = *(const float4*)&a_gat[DM + 4 * l];
    float s1 = wv.x*a1.x + wv.y*a1.y + wv.z*a1.z + wv.w*a1.w;
    float s2 = wv.x*a2.x + wv.y*a2.y + wv.z*a2.z + wv.w*a2.w;
    #pragma unroll
    for (int off = 32; off; off >>= 1) {
        s1 += __shfl_xor(s1, off, 64);
        s2 += __shfl_xor(s2, off, 64);
    }
    if (l == 0) { w1[k] = s1; w2[k] = s2; }
}

// ---------------- f1 = src@w1, f2 = src@w2 (4 rows / block) ----------------
__global__ __launch_bounds__(256) void f12_k(const float* __restrict__ src,
                                             const float* __restrict__ w1,
                                             const float* __restrict__ w2,
                                             float* __restrict__ f1,
                                             float* __restrict__ f2)
{
    const int t = threadIdx.x;
    const size_t row = (size_t)blockIdx.x * 4 + (t >> 6);
    const int l = t & 63;
    float s1 = 0.f, s2 = 0.f;
    #pragma unroll
    for (int i = 0; i < 4; i++) {
        float v = src[row * DM + l + 64*i];
        s1 = fmaf(v, w1[l + 64*i], s1);
        s2 = fmaf(v, w2[l + 64*i], s2);
    }
    #pragma unroll
    for (int off = 32; off; off >>= 1) {
        s1 += __shfl_xor(s1, off, 64);
        s2 += __shfl_xor(s2, off, 64);
    }
    if (l == 0) { f1[row] = s1; f2[row] = s2; }
}

// ---------------- bf16 MFMA GEMM: C = act(A @ B^T + bias) ----------------
// A: (M,K) bf16, lda=K. B: (N,K) bf16 rows at stride ldB.
// EP: 1 +bias->f32, 2 +bias,relu->bf16, 3 elu->f32, 5 plain->bf16, 6 qkv(+bias, Q-scaled)->bf16
template<int EP>
__global__ __launch_bounds__(256) void gemm_bf(const ushort* __restrict__ A,
                                               const ushort* __restrict__ B,
                                               const float* __restrict__ bias,
                                               float* __restrict__ Cf,
                                               ushort* __restrict__ Cb,
                                               int M, int N, int K, int ldB,
                                               long long sA, long long sB, long long sC)
{
    __shared__ ushort As[128][40];
    __shared__ ushort Bs[128][40];
    A += (size_t)blockIdx.z * sA;
    B += (size_t)blockIdx.z * sB;

    const int t  = threadIdx.x;
    const int m0 = blockIdx.y * 128, n0 = blockIdx.x * 128;
    const int lr = t >> 1, lc = (t & 1) * 16;
    const int lane = t & 63, lo = lane & 15, hi = lane >> 4;
    const int w = t >> 6;
    const int wr = (w >> 1) * 64, wc = (w & 1) * 64;

    f32x4 acc[4][4];
    f32x4 zero = {0.f, 0.f, 0.f, 0.f};
    #pragma unroll
    for (int i = 0; i < 4; i++)
        #pragma unroll
        for (int j = 0; j < 4; j++) acc[i][j] = zero;

    const ushort* Ap = A + (size_t)(m0 + lr) * K + lc;
    const ushort* Bp = B + (size_t)(n0 + lr) * ldB + lc;

    for (int k0 = 0; k0 < K; k0 += 32) {
        short8 a0 = *(const short8*)(Ap + k0);
        short8 a1 = *(const short8*)(Ap + k0 + 8);
        short8 b0 = *(const short8*)(Bp + k0);
        short8 b1 = *(const short8*)(Bp + k0 + 8);
        __syncthreads();
        *(short8*)&As[lr][lc]     = a0;
        *(short8*)&As[lr][lc + 8] = a1;
        *(short8*)&Bs[lr][lc]     = b0;
        *(short8*)&Bs[lr][lc + 8] = b1;
        __syncthreads();
        short8 afr[4], bfr[4];
        #pragma unroll
        for (int i = 0; i < 4; i++) afr[i] = *(const short8*)&As[wr + i*16 + lo][hi * 8];
        #pragma unroll
        for (int j = 0; j < 4; j++) bfr[j] = *(const short8*)&Bs[wc + j*16 + lo][hi * 8];
        #pragma unroll
        for (int i = 0; i < 4; i++)
            #pragma unroll
            for (int j = 0; j < 4; j++)
                acc[i][j] = __builtin_amdgcn_mfma_f32_16x16x32_bf16(afr[i], bfr[j], acc[i][j], 0, 0, 0);
    }

    if (EP == 2 || EP == 5 || EP == 6) Cb += (size_t)blockIdx.z * sC;
    else                               Cf += (size_t)blockIdx.z * sC;
    #pragma unroll
    for (int j = 0; j < 4; j++) {
        const int col = n0 + wc + j * 16 + lo;
        float bj = (EP == 1 || EP == 2 || EP == 6) ? bias[col] : 0.f;
        #pragma unroll
        for (int i = 0; i < 4; i++) {
            const int rbase = m0 + wr + i * 16 + hi * 4;
            #pragma unroll
            for (int r = 0; r < 4; r++) {
                float v = acc[i][j][r] + bj;
                if (EP == 3) v = v > 0.f ? v : expm1f(v);
                if (EP == 2) v = fmaxf(v, 0.f);
                if (EP == 6 && col < DM) v *= QSCALE;   // pre-scale Q for exp2-domain softmax
                if (EP == 2 || EP == 5 || EP == 6) Cb[(size_t)(rbase + r) * N + col] = f2bf(v);
                else                               Cf[(size_t)(rbase + r) * N + col] = v;
            }
        }
    }
}

// ---------------- LayerNorm(a + r) * g + b, 4 rows / block ----------------
template<bool WB>
__global__ __launch_bounds__(256) void ln_k(const float* __restrict__ a,
                                            const float* __restrict__ r,
                                            const float* __restrict__ g,
                                            const float* __restrict__ be,
                                            float* __restrict__ o,
                                            ushort* __restrict__ ob)
{
    const size_t row = (size_t)blockIdx.x * 4 + (threadIdx.x >> 6);
    const int l = threadIdx.x & 63;
    const float* pa = a + row * DM;
    const float* pr = r + row * DM;
    float v[4]; float s = 0.f;
    #pragma unroll
    for (int i = 0; i < 4; i++) { v[i] = pa[l + 64*i] + pr[l + 64*i]; s += v[i]; }
    #pragma unroll
    for (int off = 32; off; off >>= 1) s += __shfl_xor(s, off, 64);
    float mu = s * (1.0f / DM);
    float q = 0.f;
    #pragma unroll
    for (int i = 0; i < 4; i++) { float d = v[i] - mu; q += d * d; }
    #pragma unroll
    for (int off = 32; off; off >>= 1) q += __shfl_xor(q, off, 64);
    float rs = rsqrtf(q * (1.0f / DM) + EPSV);
    #pragma unroll
    for (int i = 0; i < 4; i++) {
        int c = l + 64*i;
        float out = (v[i] - mu) * rs * g[c] + be[c];
        o[row * DM + c] = out;
        if (WB) ob[row * DM + c] = f2bf(out);
    }
}

// ---------------- GAT masked softmax -> normalized P (bf16) ----------------
__global__ __launch_bounds__(256) void gat_sm_k(const int* __restrict__ adj,
                                                const float* __restrict__ f1,
                                                const float* __restrict__ f2,
                                                ushort* __restrict__ P)
{
    __shared__ float red[8];
    const int i = blockIdx.x, b = i >> 10;
    const int t = threadIdx.x;
    const int4 a4 = *(const int4*)&adj[(size_t)i * SEQ + 4 * t];
    const float4 f4 = *(const float4*)&f2[(size_t)(b << 10) + 4 * t];
    const float f1i = f1[i];
    float e[4];
    e[0] = a4.x > 0 ? f1i + f4.x : NEGV;
    e[1] = a4.y > 0 ? f1i + f4.y : NEGV;
    e[2] = a4.z > 0 ? f1i + f4.z : NEGV;
    e[3] = a4.w > 0 ? f1i + f4.w : NEGV;
    float mx = fmaxf(fmaxf(e[0], e[1]), fmaxf(e[2], e[3]));
    #pragma unroll
    for (int off = 32; off; off >>= 1) mx = fmaxf(mx, __shfl_xor(mx, off, 64));
    if ((t & 63) == 0) red[t >> 6] = mx;
    __syncthreads();
    mx = fmaxf(fmaxf(red[0], red[1]), fmaxf(red[2], red[3]));
    float s = 0.f;
    #pragma unroll
    for (int u = 0; u < 4; u++) { e[u] = __expf(e[u] - mx); s += e[u]; }
    #pragma unroll
    for (int off = 32; off; off >>= 1) s += __shfl_xor(s, off, 64);
    if ((t & 63) == 0) red[4 + (t >> 6)] = s;
    __syncthreads();
    float inv = 1.0f / (red[4] + red[5] + red[6] + red[7]);
    ushort4 o;
    o.x = f2bf(e[0] * inv); o.y = f2bf(e[1] * inv);
    o.z = f2bf(e[2] * inv); o.w = f2bf(e[3] * inv);
    *(ushort4*)&P[(size_t)i * SEQ + 4 * t] = o;
}

// ---------------- MHA v3: bf16 MFMA flash, exp2-domain, dbuf K/V, 1 barrier/tile ----------------
__device__ __forceinline__ int vt_idx(int d, int kv) { return d * 72 + ((d >> 3) & 3) * 16 + kv; }
constexpr int VTSZ = 32 * 72 + 3 * 16 + 8;

__global__ __launch_bounds__(256) void mha_k(const ushort* __restrict__ qkv,
                                             ushort* __restrict__ ctxb)
{
    __shared__ ushort Ks[2][64][40];
    __shared__ ushort Vt[2][VTSZ];
    __shared__ ushort Ps[64][72];

    const int blk = blockIdx.x;
    const int qt = blk & 15, h = (blk >> 4) & 7, b = blk >> 7;
    const int i0 = qt << 6;
    const int t = threadIdx.x;
    const int w = t >> 6, lane = t & 63, lo = lane & 15, hi = lane >> 4;
    const size_t base = (size_t)b * SEQ * 768;

    // Q fragment straight from global (pre-scaled by QSCALE in qkv epilogue)
    const short8 aQ = *(const short8*)(qkv + base + (size_t)(i0 + 16*w + lo) * 768 + h * HDIM + hi * 8);

    // stage tile 0
    const int srow = t >> 2, scb = (t & 3) << 3;
    {
        const ushort* p0 = qkv + base + (size_t)srow * 768 + h * HDIM;
        short8 k0 = *(const short8*)(p0 + 256 + scb);
        short8 v0 = *(const short8*)(p0 + 512 + scb);
        *(short8*)&Ks[0][srow][scb] = k0;
        #pragma unroll
        for (int e = 0; e < 8; e++) Vt[0][vt_idx(scb + e, srow)] = (ushort)v0[e];
    }

    float m_run[4], l_run[4];
    f32x4 O0 = {0.f, 0.f, 0.f, 0.f}, O1 = {0.f, 0.f, 0.f, 0.f};
    #pragma unroll
    for (int r = 0; r < 4; r++) { m_run[r] = -3.0e38f; l_run[r] = 0.f; }
    const f32x4 zero = {0.f, 0.f, 0.f, 0.f};

    short8 kreg, vreg;
    for (int it = 0; it < 16; it++) {
        const int cur = it & 1;
        if (it < 15) {   // issue next tile's loads early (hide HBM under compute)
            const ushort* nb = qkv + base + (size_t)((it + 1) * 64 + srow) * 768 + h * HDIM;
            kreg = *(const short8*)(nb + 256 + scb);
            vreg = *(const short8*)(nb + 512 + scb);
        }
        __syncthreads();   // Ks/Vt[cur] writes visible

        // S = Q K^T : rows q=16w+4hi+r, cols kv=16jt+lo (log2-scaled)
        f32x4 S[4];
        #pragma unroll
        for (int jt = 0; jt < 4; jt++) {
            short8 bK = *(const short8*)&Ks[cur][16 * jt + lo][hi * 8];
            S[jt] = __builtin_amdgcn_mfma_f32_16x16x32_bf16(aQ, bK, zero, 0, 0, 0);
        }

        // online softmax in exp2 domain, defer-rescale (THR=8 -> P <= 2^8)
        #pragma unroll
        for (int r = 0; r < 4; r++) {
            float mx = fmaxf(fmaxf(S[0][r], S[1][r]), fmaxf(S[2][r], S[3][r]));
            #pragma unroll
            for (int off = 8; off; off >>= 1) mx = fmaxf(mx, __shfl_xor(mx, off, 16));
            if (mx > m_run[r] + 8.f) {
                float sc = exp2f(m_run[r] - mx);
                m_run[r] = mx;
                l_run[r] *= sc; O0[r] *= sc; O1[r] *= sc;
            }
            float p0 = exp2f(S[0][r] - m_run[r]);
            float p1 = exp2f(S[1][r] - m_run[r]);
            float p2 = exp2f(S[2][r] - m_run[r]);
            float p3 = exp2f(S[3][r] - m_run[r]);
            float rsum = (p0 + p1) + (p2 + p3);
            #pragma unroll
            for (int off = 8; off; off >>= 1) rsum += __shfl_xor(rsum, off, 16);
            l_run[r] += rsum;
            const int row = 16 * w + 4 * hi + r;
            unsigned u01 = cvt_pk_bf16(p0, p1);
            unsigned u23 = cvt_pk_bf16(p2, p3);
            Ps[row][lo]      = (ushort)u01;
            Ps[row][lo + 16] = (ushort)(u01 >> 16);
            Ps[row][lo + 32] = (ushort)u23;
            Ps[row][lo + 48] = (ushort)(u23 >> 16);
        }

        // O += P V   (Ps rows 16w..16w+15 wave-private: no barrier)
        #pragma unroll
        for (int kt = 0; kt < 2; kt++) {
            short8 aP  = *(const short8*)&Ps[16 * w + lo][32 * kt + hi * 8];
            short8 bV0 = *(const short8*)&Vt[cur][vt_idx(lo,      32 * kt + hi * 8)];
            short8 bV1 = *(const short8*)&Vt[cur][vt_idx(16 + lo, 32 * kt + hi * 8)];
            O0 = __builtin_amdgcn_mfma_f32_16x16x32_bf16(aP, bV0, O0, 0, 0, 0);
            O1 = __builtin_amdgcn_mfma_f32_16x16x32_bf16(aP, bV1, O1, 0, 0, 0);
        }

        if (it < 15) {   // write next tile into the other buffer (prev reads fenced by this iter's barrier)
            *(short8*)&Ks[cur ^ 1][srow][scb] = kreg;
            #pragma unroll
            for (int e = 0; e < 8; e++) Vt[cur ^ 1][vt_idx(scb + e, srow)] = (ushort)vreg[e];
        }
    }

    #pragma unroll
    for (int r = 0; r < 4; r++) {
        float inv = 1.0f / l_run[r];
        size_t row = (size_t)b * SEQ + i0 + 16 * w + 4 * hi + r;
        ctxb[row * DM + h * HDIM + lo]      = f2bf(O0[r] * inv);
        ctxb[row * DM + h * HDIM + 16 + lo] = f2bf(O1[r] * inv);
    }
}

extern "C" void kernel_launch(void* const* d_in, const int* in_sizes, int n_in,
                              void* d_out, int out_size, void* d_ws, size_t ws_size,
                              hipStream_t stream)
{
    const float* src        = (const float*)d_in[0];
    const int*   adj        = (const int*)  d_in[1];
    const float* W_gat      = (const float*)d_in[2];
    const float* a_gat      = (const float*)d_in[3];
    const float* in_proj_w  = (const float*)d_in[4];
    const float* in_proj_b  = (const float*)d_in[5];
    const float* out_proj_w = (const float*)d_in[6];
    const float* out_proj_b = (const float*)d_in[7];
    const float* lin1_w     = (const float*)d_in[8];
    const float* lin1_b     = (const float*)d_in[9];
    const float* lin2_w     = (const float*)d_in[10];
    const float* lin2_b     = (const float*)d_in[11];
    const float* ln1_g      = (const float*)d_in[12];
    const float* ln1_b_     = (const float*)d_in[13];
    const float* ln2_g      = (const float*)d_in[14];
    const float* ln2_b_     = (const float*)d_in[15];
    const float* ln3_g      = (const float*)d_in[16];
    const float* ln3_b_     = (const float*)d_in[17];

    char* base = (char*)d_ws;
    const size_t MB = 1024 * 1024;
    float*  tmp   = (float*) (base + 0 * MB);    // 8 MB
    float*  x     = (float*) (base + 8 * MB);    // 8 MB
    float*  y     = (float*) (base + 16 * MB);   // 8 MB
    // BIG shared region [24MB, 56MB): P_bf -> qkvb -> ff1b (sequential lifetimes)
    ushort* P_bf  = (ushort*)(base + 24 * MB);   // 16 MB
    ushort* qkvb  = (ushort*)(base + 24 * MB);   // 12 MB
    ushort* ff1b  = (ushort*)(base + 24 * MB);   // 32 MB
    ushort* srcb  = (ushort*)(base + 56 * MB);   // 4 MB
    ushort* WhTb  = (ushort*)(base + 60 * MB);   // 4 MB  ([256][8192] bf16)
    ushort* xb    = (ushort*)(base + 64 * MB);   // 4 MB
    ushort* yb    = (ushort*)(base + 68 * MB);   // 4 MB
    ushort* ctxb  = (ushort*)(base + 72 * MB);   // 4 MB
    float*  f1    = (float*) (base + 76 * MB);   // 32 KB
    float*  f2    = f1 + ROWS;                   // 32 KB
    float*  w1    = f2 + ROWS;                   // 1 KB
    float*  w2    = w1 + DM;                     // 1 KB
    ushort* wgTb  = (ushort*)(base + 77 * MB);   // 128 KB
    ushort* ipwb  = wgTb + 65536;                // 384 KB
    ushort* opwb  = ipwb + 196608;               // 128 KB
    ushort* l1wb  = opwb + 65536;                // 1 MB
    ushort* l2wb  = l1wb + 524288;               // 1 MB

    dim3 b256(256);

    // --- casts (one fused dispatch + W_gat transpose) ---
    CastArgs ca;
    ca.in[0] = src;       ca.out[0] = srcb; ca.n4[0] = 2097152 / 4;
    ca.in[1] = in_proj_w; ca.out[1] = ipwb; ca.n4[1] = 196608 / 4;
    ca.in[2] = out_proj_w;ca.out[2] = opwb; ca.n4[2] = 65536 / 4;
    ca.in[3] = lin1_w;    ca.out[3] = l1wb; ca.n4[3] = 524288 / 4;
    ca.in[4] = lin2_w;    ca.out[4] = l2wb; ca.n4[4] = 524288 / 4;
    castall_k<<<(2097152 + 196608 + 65536 + 524288 + 524288) / 4 / 256, b256, 0, stream>>>(ca);
    tcast_k<<<dim3(8, 8), b256, 0, stream>>>(W_gat, wgTb, 256, 256);

    // --- GAT: f1/f2 via associativity (no fp32 Wh needed) ---
    w12_k<<<64, b256, 0, stream>>>(W_gat, a_gat, w1, w2);
    f12_k<<<ROWS / 4, b256, 0, stream>>>(src, w1, w2, f1, f2);
    // WhT = (src @ W_gat)^T = W_gat^T @ src^T, bf16 [256][8192]
    gemm_bf<5><<<dim3(64, 2, 1), b256, 0, stream>>>(wgTb, srcb, nullptr, nullptr, WhTb,
                                                    DM, ROWS, DM, DM, 0, 0, 0);
    gat_sm_k<<<ROWS, b256, 0, stream>>>(adj, f1, f2, P_bf);
    // graph_out = elu(P @ Wh): B = WhT batch slice (col offset b*1024, row stride 8192)
    gemm_bf<3><<<dim3(2, 8, 8), b256, 0, stream>>>(P_bf, WhTb, nullptr, tmp, nullptr,
                                                   SEQ, DM, SEQ, ROWS,
                                                   (long long)SEQ * SEQ, (long long)SEQ, (long long)SEQ * DM);
    ln_k<true><<<ROWS / 4, b256, 0, stream>>>(src, tmp, ln1_g, ln1_b_, x, xb);

    // --- MHA (Q pre-scaled in epilogue) ---
    gemm_bf<6><<<dim3(6, 64, 1), b256, 0, stream>>>(xb, ipwb, in_proj_b, nullptr, qkvb,
                                                    ROWS, 768, DM, DM, 0, 0, 0);
    mha_k<<<BATCH * NH * (SEQ / 64), b256, 0, stream>>>(qkvb, ctxb);
    gemm_bf<1><<<dim3(2, 64, 1), b256, 0, stream>>>(ctxb, opwb, out_proj_b, tmp, nullptr,
                                                    ROWS, DM, DM, DM, 0, 0, 0);
    ln_k<true><<<ROWS / 4, b256, 0, stream>>>(x, tmp, ln2_g, ln2_b_, y, yb);

    // --- FFN ---
    gemm_bf<2><<<dim3(16, 64, 1), b256, 0, stream>>>(yb, l1wb, lin1_b, nullptr, ff1b,
                                                     ROWS, DF, DM, DM, 0, 0, 0);
    gemm_bf<1><<<dim3(2, 64, 1), b256, 0, stream>>>(ff1b, l2wb, lin2_b, tmp, nullptr,
                                                    ROWS, DM, DF, DF, 0, 0, 0);
    ln_k<false><<<ROWS / 4, b256, 0, stream>>>(y, tmp, ln3_g, ln3_b_, (float*)d_out, nullptr);
}

// Round 7
// 188.341 us; speedup vs baseline: 10.4541x; 1.2553x over previous
//
#include <hip/hip_runtime.h>
#include <math.h>

constexpr int BATCH = 8;
constexpr int SEQ   = 1024;
constexpr int DM    = 256;
constexpr int DF    = 2048;
constexpr int NH    = 8;
constexpr int HDIM  = 32;
constexpr int ROWS  = BATCH * SEQ;    // 8192
constexpr float NEGV = -9e15f;
constexpr float EPSV = 1e-5f;
constexpr float QSCALE = 0.2550351822f;   // 1/sqrt(32) * log2(e)
constexpr float LOG2E  = 1.44269504f;

typedef __attribute__((ext_vector_type(8))) short short8;
typedef __attribute__((ext_vector_type(4))) float f32x4;

static __device__ __forceinline__ ushort f2bf(float f) {
    unsigned x = __float_as_uint(f);
    unsigned r = (x + 0x7fffu + ((x >> 16) & 1u)) >> 16;   // RNE
    return (ushort)r;
}
static __device__ __forceinline__ unsigned cvt_pk_bf16(float lo, float hi) {
    unsigned r;
    asm volatile("v_cvt_pk_bf16_f32 %0, %1, %2" : "=v"(r) : "v"(lo), "v"(hi));
    return r;
}

// ---------------- fused fp32 -> bf16 cast of 5 regions ----------------
struct CastArgs {
    const float* in[5];
    ushort* out[5];
    int n4[5];
};
__global__ __launch_bounds__(256) void castall_k(CastArgs a)
{
    int idx = blockIdx.x * 256 + threadIdx.x;
    #pragma unroll
    for (int r = 0; r < 5; r++) {
        if (idx < a.n4[r]) {
            float4 v = *(const float4*)&a.in[r][(size_t)idx * 4];
            ushort4 o; o.x = f2bf(v.x); o.y = f2bf(v.y); o.z = f2bf(v.z); o.w = f2bf(v.w);
            *(ushort4*)&a.out[r][(size_t)idx * 4] = o;
            return;
        }
        idx -= a.n4[r];
    }
}

// ---------------- transpose-cast: Out[c][r] = bf16(In[r][c]) ----------------
__global__ __launch_bounds__(256) void tcast_k(const float* __restrict__ In,
                                               ushort* __restrict__ Out,
                                               int R, int C)
{
    __shared__ float Ts[32][33];
    const int r0 = blockIdx.y * 32, c0 = blockIdx.x * 32;
    const int t = threadIdx.x;
    const int lr = t >> 3, lc4 = (t & 7) * 4;
    float4 v = *(const float4*)&In[(size_t)(r0 + lr) * C + c0 + lc4];
    Ts[lr][lc4] = v.x; Ts[lr][lc4 + 1] = v.y; Ts[lr][lc4 + 2] = v.z; Ts[lr][lc4 + 3] = v.w;
    __syncthreads();
    const int oc = t >> 3, or4 = (t & 7) * 4;
    ushort4 o;
    o.x = f2bf(Ts[or4 + 0][oc]); o.y = f2bf(Ts[or4 + 1][oc]);
    o.z = f2bf(Ts[or4 + 2][oc]); o.w = f2bf(Ts[or4 + 3][oc]);
    *(ushort4*)&Out[(size_t)(c0 + oc) * R + r0 + or4] = o;
}

// ---------------- w1 = W_gat @ a1, w2 = W_gat @ a2 ----------------
__global__ __launch_bounds__(256) void w12_k(const float* __restrict__ W_gat,
                                             const float* __restrict__ a_gat,
                                             float* __restrict__ w1,
                                             float* __restrict__ w2)
{
    const int t = threadIdx.x;
    const int k = blockIdx.x * 4 + (t >> 6);
    const int l = t & 63;
    float4 wv = *(const float4*)&W_gat[(size_t)k * DM + 4 * l];
    float4 a1 = *(const float4*)&a_gat[4 * l];
    float4 a2 = *(const float4*)&a_gat[DM + 4 * l];
    float s1 = wv.x*a1.x + wv.y*a1.y + wv.z*a1.z + wv.w*a1.w;
    float s2 = wv.x*a2.x + wv.y*a2.y + wv.z*a2.z + wv.w*a2.w;
    #pragma unroll
    for (int off = 32; off; off >>= 1) {
        s1 += __shfl_xor(s1, off, 64);
        s2 += __shfl_xor(s2, off, 64);
    }
    if (l == 0) { w1[k] = s1; w2[k] = s2; }
}

// ---------------- f1 = log2e*(src@w1), f2 = log2e*(src@w2) ----------------
__global__ __launch_bounds__(256) void f12_k(const float* __restrict__ src,
                                             const float* __restrict__ w1,
                                             const float* __restrict__ w2,
                                             float* __restrict__ f1,
                                             float* __restrict__ f2)
{
    const int t = threadIdx.x;
    const size_t row = (size_t)blockIdx.x * 4 + (t >> 6);
    const int l = t & 63;
    float s1 = 0.f, s2 = 0.f;
    #pragma unroll
    for (int i = 0; i < 4; i++) {
        float v = src[row * DM + l + 64*i];
        s1 = fmaf(v, w1[l + 64*i], s1);
        s2 = fmaf(v, w2[l + 64*i], s2);
    }
    #pragma unroll
    for (int off = 32; off; off >>= 1) {
        s1 += __shfl_xor(s1, off, 64);
        s2 += __shfl_xor(s2, off, 64);
    }
    if (l == 0) { f1[row] = s1 * LOG2E; f2[row] = s2 * LOG2E; }
}

// ---------------- bf16 MFMA GEMM: C = act(A @ B^T + bias), BM=128, BN in {128,64} ----------------
// EP: 1 +bias->f32, 2 +bias,relu->bf16, 3 elu->f32, 5 plain->bf16, 6 qkv(+bias, Q-scaled)->bf16
template<int EP, int BN>
__global__ __launch_bounds__(256) void gemm_bf(const ushort* __restrict__ A,
                                               const ushort* __restrict__ B,
                                               const float* __restrict__ bias,
                                               float* __restrict__ Cf,
                                               ushort* __restrict__ Cb,
                                               int M, int N, int K, int ldB,
                                               long long sA, long long sB, long long sC)
{
    __shared__ ushort As[128][40];
    __shared__ ushort Bs[BN][40];
    A += (size_t)blockIdx.z * sA;
    B += (size_t)blockIdx.z * sB;

    const int t  = threadIdx.x;
    const int m0 = blockIdx.y * 128, n0 = blockIdx.x * BN;
    const int lane = t & 63, lo = lane & 15, hi = lane >> 4;
    const int w = t >> 6;
    constexpr int NJ = BN / 32;                         // B fragments per wave
    const int wr = (w >> 1) * 64;
    const int wc = (w & 1) * (BN / 2);

    const int lrA = t >> 1, lcA = (t & 1) * 16;
    const int lrB = (BN == 128) ? (t >> 1) : (t >> 2);
    const int lcB = (BN == 128) ? ((t & 1) * 16) : ((t & 3) * 8);

    f32x4 acc[4][NJ];
    const f32x4 zero = {0.f, 0.f, 0.f, 0.f};
    #pragma unroll
    for (int i = 0; i < 4; i++)
        #pragma unroll
        for (int j = 0; j < NJ; j++) acc[i][j] = zero;

    const ushort* Ap = A + (size_t)(m0 + lrA) * K + lcA;
    const ushort* Bp = B + (size_t)(n0 + lrB) * ldB + lcB;

    for (int k0 = 0; k0 < K; k0 += 32) {
        short8 a0 = *(const short8*)(Ap + k0);
        short8 a1 = *(const short8*)(Ap + k0 + 8);
        short8 b0 = *(const short8*)(Bp + k0);
        short8 b1;
        if (BN == 128) b1 = *(const short8*)(Bp + k0 + 8);
        __syncthreads();
        *(short8*)&As[lrA][lcA]     = a0;
        *(short8*)&As[lrA][lcA + 8] = a1;
        *(short8*)&Bs[lrB][lcB] = b0;
        if (BN == 128) *(short8*)&Bs[lrB][lcB + 8] = b1;
        __syncthreads();
        short8 afr[4], bfr[NJ];
        #pragma unroll
        for (int i = 0; i < 4; i++) afr[i] = *(const short8*)&As[wr + i*16 + lo][hi * 8];
        #pragma unroll
        for (int j = 0; j < NJ; j++) bfr[j] = *(const short8*)&Bs[wc + j*16 + lo][hi * 8];
        #pragma unroll
        for (int i = 0; i < 4; i++)
            #pragma unroll
            for (int j = 0; j < NJ; j++)
                acc[i][j] = __builtin_amdgcn_mfma_f32_16x16x32_bf16(afr[i], bfr[j], acc[i][j], 0, 0, 0);
    }

    if (EP == 2 || EP == 5 || EP == 6) Cb += (size_t)blockIdx.z * sC;
    else                               Cf += (size_t)blockIdx.z * sC;
    #pragma unroll
    for (int j = 0; j < NJ; j++) {
        const int col = n0 + wc + j * 16 + lo;
        float bj = (EP == 1 || EP == 2 || EP == 6) ? bias[col] : 0.f;
        #pragma unroll
        for (int i = 0; i < 4; i++) {
            const int rbase = m0 + wr + i * 16 + hi * 4;
            #pragma unroll
            for (int r = 0; r < 4; r++) {
                float v = acc[i][j][r] + bj;
                if (EP == 3) v = v > 0.f ? v : expm1f(v);
                if (EP == 2) v = fmaxf(v, 0.f);
                if (EP == 6 && col < DM) v *= QSCALE;
                if (EP == 2 || EP == 5 || EP == 6) Cb[(size_t)(rbase + r) * N + col] = f2bf(v);
                else                               Cf[(size_t)(rbase + r) * N + col] = v;
            }
        }
    }
}

// ---------------- LayerNorm(a + r) * g + b, 4 rows / block ----------------
template<bool WB>
__global__ __launch_bounds__(256) void ln_k(const float* __restrict__ a,
                                            const float* __restrict__ r,
                                            const float* __restrict__ g,
                                            const float* __restrict__ be,
                                            float* __restrict__ o,
                                            ushort* __restrict__ ob)
{
    const size_t row = (size_t)blockIdx.x * 4 + (threadIdx.x >> 6);
    const int l = threadIdx.x & 63;
    const float* pa = a + row * DM;
    const float* pr = r + row * DM;
    float v[4]; float s = 0.f;
    #pragma unroll
    for (int i = 0; i < 4; i++) { v[i] = pa[l + 64*i] + pr[l + 64*i]; s += v[i]; }
    #pragma unroll
    for (int off = 32; off; off >>= 1) s += __shfl_xor(s, off, 64);
    float mu = s * (1.0f / DM);
    float q = 0.f;
    #pragma unroll
    for (int i = 0; i < 4; i++) { float d = v[i] - mu; q += d * d; }
    #pragma unroll
    for (int off = 32; off; off >>= 1) q += __shfl_xor(q, off, 64);
    float rs = rsqrtf(q * (1.0f / DM) + EPSV);
    #pragma unroll
    for (int i = 0; i < 4; i++) {
        int c = l + 64*i;
        float out = (v[i] - mu) * rs * g[c] + be[c];
        o[row * DM + c] = out;
        if (WB) ob[row * DM + c] = f2bf(out);
    }
}

// ---------------- GAT masked softmax (exp2 domain) -> normalized P (bf16) ----------------
__global__ __launch_bounds__(256) void gat_sm_k(const int* __restrict__ adj,
                                                const float* __restrict__ f1,
                                                const float* __restrict__ f2,
                                                ushort* __restrict__ P)
{
    __shared__ float red[8];
    const int i = blockIdx.x, b = i >> 10;
    const int t = threadIdx.x;
    const int4 a4 = *(const int4*)&adj[(size_t)i * SEQ + 4 * t];
    const float4 f4 = *(const float4*)&f2[(size_t)(b << 10) + 4 * t];
    const float f1i = f1[i];
    float e[4];
    e[0] = a4.x > 0 ? f1i + f4.x : NEGV;
    e[1] = a4.y > 0 ? f1i + f4.y : NEGV;
    e[2] = a4.z > 0 ? f1i + f4.z : NEGV;
    e[3] = a4.w > 0 ? f1i + f4.w : NEGV;
    float mx = fmaxf(fmaxf(e[0], e[1]), fmaxf(e[2], e[3]));
    #pragma unroll
    for (int off = 32; off; off >>= 1) mx = fmaxf(mx, __shfl_xor(mx, off, 64));
    if ((t & 63) == 0) red[t >> 6] = mx;
    __syncthreads();
    mx = fmaxf(fmaxf(red[0], red[1]), fmaxf(red[2], red[3]));
    float s = 0.f;
    #pragma unroll
    for (int u = 0; u < 4; u++) { e[u] = exp2f(e[u] - mx); s += e[u]; }
    #pragma unroll
    for (int off = 32; off; off >>= 1) s += __shfl_xor(s, off, 64);
    if ((t & 63) == 0) red[4 + (t >> 6)] = s;
    __syncthreads();
    float inv = 1.0f / (red[4] + red[5] + red[6] + red[7]);
    ushort4 o;
    o.x = f2bf(e[0] * inv); o.y = f2bf(e[1] * inv);
    o.z = f2bf(e[2] * inv); o.w = f2bf(e[3] * inv);
    *(ushort4*)&P[(size_t)i * SEQ + 4 * t] = o;
}

// ---------------- MHA v4: ballot-gated defer-max, MFMA row-sum, packed P stores ----------------
// kv storage permutation pi: col 2c   <-> kv c      (c<16, per 32-col half)
//                            col 2c+1 <-> kv c+16
// applied consistently to Ps writes and Vt staging; PV sums over kv so any
// consistent permutation is exact.
__device__ __forceinline__ int vt_idx(int d, int kv) { return d * 72 + ((d >> 3) & 3) * 16 + kv; }
constexpr int VTSZ = 32 * 72 + 3 * 16 + 8;

__global__ __launch_bounds__(256) void mha_k(const ushort* __restrict__ qkv,
                                             ushort* __restrict__ ctxb)
{
    __shared__ ushort Ks[2][64][40];
    __shared__ ushort Vt[2][VTSZ];
    __shared__ ushort Ps[64][72];

    const int blk = blockIdx.x;
    const int qt = blk & 15, h = (blk >> 4) & 7, b = blk >> 7;
    const int i0 = qt << 6;
    const int t = threadIdx.x;
    const int w = t >> 6, lane = t & 63, lo = lane & 15, hi = lane >> 4;
    const int gsh = lane & 48;              // ballot group base
    const size_t base = (size_t)b * SEQ * 768;

    // Q fragment from global (pre-scaled by QSCALE in qkv epilogue)
    const short8 aQ = *(const short8*)(qkv + base + (size_t)(i0 + 16*w + lo) * 768 + h * HDIM + hi * 8);
    short8 ones;
    #pragma unroll
    for (int e = 0; e < 8; e++) ones[e] = (short)0x3F80;   // bf16 1.0

    const int srow = t >> 2, scb = (t & 3) << 3;
    const int vcol = (srow & 32) | ((srow & 15) << 1) | ((srow >> 4) & 1);  // pi^-1(srow)
    {   // stage tile 0
        const ushort* p0 = qkv + base + (size_t)srow * 768 + h * HDIM;
        short8 k0 = *(const short8*)(p0 + 256 + scb);
        short8 v0 = *(const short8*)(p0 + 512 + scb);
        *(short8*)&Ks[0][srow][scb] = k0;
        #pragma unroll
        for (int e = 0; e < 8; e++) Vt[0][vt_idx(scb + e, vcol)] = (ushort)v0[e];
    }

    float m_run[4], l_run[4];
    f32x4 O0 = {0.f, 0.f, 0.f, 0.f}, O1 = {0.f, 0.f, 0.f, 0.f};
    #pragma unroll
    for (int r = 0; r < 4; r++) { m_run[r] = -3.0e38f; l_run[r] = 0.f; }
    const f32x4 zero = {0.f, 0.f, 0.f, 0.f};

    short8 kreg, vreg;
    for (int it = 0; it < 16; it++) {
        const int cur = it & 1;
        if (it < 15) {
            const ushort* nb = qkv + base + (size_t)((it + 1) * 64 + srow) * 768 + h * HDIM;
            kreg = *(const short8*)(nb + 256 + scb);
            vreg = *(const short8*)(nb + 512 + scb);
        }
        __syncthreads();

        // S = Q K^T : lane owns rows q=16w+4hi+r, cols kv=16jt+lo (log2-scaled)
        f32x4 S[4];
        #pragma unroll
        for (int jt = 0; jt < 4; jt++) {
            short8 bK = *(const short8*)&Ks[cur][16 * jt + lo][hi * 8];
            S[jt] = __builtin_amdgcn_mfma_f32_16x16x32_bf16(aQ, bK, zero, 0, 0, 0);
        }

        // defer-max: cross-lane reduce + rescale ONLY if some lane grew > THR=8
        float mxl[4];
        bool any = false;
        #pragma unroll
        for (int r = 0; r < 4; r++) {
            mxl[r] = fmaxf(fmaxf(S[0][r], S[1][r]), fmaxf(S[2][r], S[3][r]));
            any = any || (mxl[r] > m_run[r] + 8.f);
        }
        unsigned long long bal = __ballot(any);
        if ((bal >> gsh) & 0xffffULL) {
            #pragma unroll
            for (int r = 0; r < 4; r++) {
                float mx = mxl[r];
                #pragma unroll
                for (int off = 8; off; off >>= 1) mx = fmaxf(mx, __shfl_xor(mx, off, 16));
                float mnew = fmaxf(m_run[r], mx);
                float sc = exp2f(m_run[r] - mnew);
                m_run[r] = mnew;
                l_run[r] *= sc; O0[r] *= sc; O1[r] *= sc;
            }
        }
        // P = exp2(S - m), packed u32 stores under pi
        #pragma unroll
        for (int r = 0; r < 4; r++) {
            const int row = 16 * w + 4 * hi + r;
            unsigned u01 = cvt_pk_bf16(exp2f(S[0][r] - m_run[r]), exp2f(S[1][r] - m_run[r]));
            unsigned u23 = cvt_pk_bf16(exp2f(S[2][r] - m_run[r]), exp2f(S[3][r] - m_run[r]));
            *(unsigned*)&Ps[row][2 * lo]      = u01;
            *(unsigned*)&Ps[row][32 + 2 * lo] = u23;
        }

        // O += P V ; row-sum l += P @ 1 via matrix pipe (no shuffles)
        f32x4 O2 = zero;
        #pragma unroll
        for (int kt = 0; kt < 2; kt++) {
            short8 aP  = *(const short8*)&Ps[16 * w + lo][32 * kt + hi * 8];
            short8 bV0 = *(const short8*)&Vt[cur][vt_idx(lo,      32 * kt + hi * 8)];
            short8 bV1 = *(const short8*)&Vt[cur][vt_idx(16 + lo, 32 * kt + hi * 8)];
            O0 = __builtin_amdgcn_mfma_f32_16x16x32_bf16(aP, bV0, O0, 0, 0, 0);
            O1 = __builtin_amdgcn_mfma_f32_16x16x32_bf16(aP, bV1, O1, 0, 0, 0);
            O2 = __builtin_amdgcn_mfma_f32_16x16x32_bf16(aP, ones, O2, 0, 0, 0);
        }
        #pragma unroll
        for (int r = 0; r < 4; r++) l_run[r] += O2[r];

        if (it < 15) {
            *(short8*)&Ks[cur ^ 1][srow][scb] = kreg;
            #pragma unroll
            for (int e = 0; e < 8; e++) Vt[cur ^ 1][vt_idx(scb + e, vcol)] = (ushort)vreg[e];
        }
    }

    #pragma unroll
    for (int r = 0; r < 4; r++) {
        float inv = 1.0f / l_run[r];
        size_t row = (size_t)b * SEQ + i0 + 16 * w + 4 * hi + r;
        ctxb[row * DM + h * HDIM + lo]      = f2bf(O0[r] * inv);
        ctxb[row * DM + h * HDIM + 16 + lo] = f2bf(O1[r] * inv);
    }
}

extern "C" void kernel_launch(void* const* d_in, const int* in_sizes, int n_in,
                              void* d_out, int out_size, void* d_ws, size_t ws_size,
                              hipStream_t stream)
{
    const float* src        = (const float*)d_in[0];
    const int*   adj        = (const int*)  d_in[1];
    const float* W_gat      = (const float*)d_in[2];
    const float* a_gat      = (const float*)d_in[3];
    const float* in_proj_w  = (const float*)d_in[4];
    const float* in_proj_b  = (const float*)d_in[5];
    const float* out_proj_w = (const float*)d_in[6];
    const float* out_proj_b = (const float*)d_in[7];
    const float* lin1_w     = (const float*)d_in[8];
    const float* lin1_b     = (const float*)d_in[9];
    const float* lin2_w     = (const float*)d_in[10];
    const float* lin2_b     = (const float*)d_in[11];
    const float* ln1_g      = (const float*)d_in[12];
    const float* ln1_b_     = (const float*)d_in[13];
    const float* ln2_g      = (const float*)d_in[14];
    const float* ln2_b_     = (const float*)d_in[15];
    const float* ln3_g      = (const float*)d_in[16];
    const float* ln3_b_     = (const float*)d_in[17];

    char* base = (char*)d_ws;
    const size_t MB = 1024 * 1024;
    float*  tmp   = (float*) (base + 0 * MB);    // 8 MB
    float*  x     = (float*) (base + 8 * MB);    // 8 MB
    float*  y     = (float*) (base + 16 * MB);   // 8 MB
    ushort* P_bf  = (ushort*)(base + 24 * MB);   // 16 MB (then qkvb / ff1b)
    ushort* qkvb  = (ushort*)(base + 24 * MB);
    ushort* ff1b  = (ushort*)(base + 24 * MB);
    ushort* srcb  = (ushort*)(base + 56 * MB);   // 4 MB
    ushort* WhTb  = (ushort*)(base + 60 * MB);   // 4 MB ([256][8192])
    ushort* xb    = (ushort*)(base + 64 * MB);   // 4 MB
    ushort* yb    = (ushort*)(base + 68 * MB);   // 4 MB
    ushort* ctxb  = (ushort*)(base + 72 * MB);   // 4 MB
    float*  f1    = (float*) (base + 76 * MB);
    float*  f2    = f1 + ROWS;
    float*  w1    = f2 + ROWS;
    float*  w2    = w1 + DM;
    ushort* wgTb  = (ushort*)(base + 77 * MB);
    ushort* ipwb  = wgTb + 65536;
    ushort* opwb  = ipwb + 196608;
    ushort* l1wb  = opwb + 65536;
    ushort* l2wb  = l1wb + 524288;

    dim3 b256(256);

    CastArgs ca;
    ca.in[0] = src;       ca.out[0] = srcb; ca.n4[0] = 2097152 / 4;
    ca.in[1] = in_proj_w; ca.out[1] = ipwb; ca.n4[1] = 196608 / 4;
    ca.in[2] = out_proj_w;ca.out[2] = opwb; ca.n4[2] = 65536 / 4;
    ca.in[3] = lin1_w;    ca.out[3] = l1wb; ca.n4[3] = 524288 / 4;
    ca.in[4] = lin2_w;    ca.out[4] = l2wb; ca.n4[4] = 524288 / 4;
    castall_k<<<(2097152 + 196608 + 65536 + 524288 + 524288) / 4 / 256, b256, 0, stream>>>(ca);
    tcast_k<<<dim3(8, 8), b256, 0, stream>>>(W_gat, wgTb, 256, 256);

    // --- GAT ---
    w12_k<<<64, b256, 0, stream>>>(W_gat, a_gat, w1, w2);
    f12_k<<<ROWS / 4, b256, 0, stream>>>(src, w1, w2, f1, f2);
    // WhT = W_gat^T @ src^T -> bf16 [256][8192]
    gemm_bf<5, 64><<<dim3(ROWS/64, 2, 1), b256, 0, stream>>>(wgTb, srcb, nullptr, nullptr, WhTb,
                                                             DM, ROWS, DM, DM, 0, 0, 0);
    gat_sm_k<<<ROWS, b256, 0, stream>>>(adj, f1, f2, P_bf);
    gemm_bf<3, 64><<<dim3(4, 8, 8), b256, 0, stream>>>(P_bf, WhTb, nullptr, tmp, nullptr,
                                                       SEQ, DM, SEQ, ROWS,
                                                       (long long)SEQ * SEQ, (long long)SEQ, (long long)SEQ * DM);
    ln_k<true><<<ROWS / 4, b256, 0, stream>>>(src, tmp, ln1_g, ln1_b_, x, xb);

    // --- MHA ---
    gemm_bf<6, 128><<<dim3(6, 64, 1), b256, 0, stream>>>(xb, ipwb, in_proj_b, nullptr, qkvb,
                                                         ROWS, 768, DM, DM, 0, 0, 0);
    mha_k<<<BATCH * NH * (SEQ / 64), b256, 0, stream>>>(qkvb, ctxb);
    gemm_bf<1, 64><<<dim3(4, 64, 1), b256, 0, stream>>>(ctxb, opwb, out_proj_b, tmp, nullptr,
                                                        ROWS, DM, DM, DM, 0, 0, 0);
    ln_k<true><<<ROWS / 4, b256, 0, stream>>>(x, tmp, ln2_g, ln2_b_, y, yb);

    // --- FFN ---
    gemm_bf<2, 128><<<dim3(16, 64, 1), b256, 0, stream>>>(yb, l1wb, lin1_b, nullptr, ff1b,
                                                          ROWS, DF, DM, DM, 0, 0, 0);
    gemm_bf<1, 64><<<dim3(4, 64, 1), b256, 0, stream>>>(ff1b, l2wb, lin2_b, tmp, nullptr,
                                                        ROWS, DM, DF, DF, 0, 0, 0);
    ln_k<false><<<ROWS / 4, b256, 0, stream>>>(y, tmp, ln3_g, ln3_b_, (float*)d_out, nullptr);
}

// Round 8
// 166.992 us; speedup vs baseline: 11.7906x; 1.1278x over previous
//
#include <hip/hip_runtime.h>
#include <math.h>

constexpr int BATCH = 8;
constexpr int SEQ   = 1024;
constexpr int DM    = 256;
constexpr int DF    = 2048;
constexpr int NH    = 8;
constexpr int HDIM  = 32;
constexpr int ROWS  = BATCH * SEQ;    // 8192
constexpr float NEGV = -9e15f;
constexpr float EPSV = 1e-5f;
constexpr float QSCALE = 0.2550351822f;   // 1/sqrt(32) * log2(e)
constexpr float LOG2E  = 1.44269504f;

typedef __attribute__((ext_vector_type(8))) short short8;
typedef __attribute__((ext_vector_type(4))) float f32x4;

static __device__ __forceinline__ ushort f2bf(float f) {
    unsigned x = __float_as_uint(f);
    unsigned r = (x + 0x7fffu + ((x >> 16) & 1u)) >> 16;   // RNE
    return (ushort)r;
}
static __device__ __forceinline__ unsigned cvt_pk_bf16(float lo, float hi) {
    unsigned r;
    asm volatile("v_cvt_pk_bf16_f32 %0, %1, %2" : "=v"(r) : "v"(lo), "v"(hi));
    return r;
}

// ---------------- fused fp32 -> bf16 cast of 5 regions ----------------
struct CastArgs {
    const float* in[5];
    ushort* out[5];
    int n4[5];
};
__global__ __launch_bounds__(256) void castall_k(CastArgs a)
{
    int idx = blockIdx.x * 256 + threadIdx.x;
    #pragma unroll
    for (int r = 0; r < 5; r++) {
        if (idx < a.n4[r]) {
            float4 v = *(const float4*)&a.in[r][(size_t)idx * 4];
            ushort4 o; o.x = f2bf(v.x); o.y = f2bf(v.y); o.z = f2bf(v.z); o.w = f2bf(v.w);
            *(ushort4*)&a.out[r][(size_t)idx * 4] = o;
            return;
        }
        idx -= a.n4[r];
    }
}

// ---------------- transpose-cast: Out[c][r] = bf16(In[r][c]) ----------------
__global__ __launch_bounds__(256) void tcast_k(const float* __restrict__ In,
                                               ushort* __restrict__ Out,
                                               int R, int C)
{
    __shared__ float Ts[32][33];
    const int r0 = blockIdx.y * 32, c0 = blockIdx.x * 32;
    const int t = threadIdx.x;
    const int lr = t >> 3, lc4 = (t & 7) * 4;
    float4 v = *(const float4*)&In[(size_t)(r0 + lr) * C + c0 + lc4];
    Ts[lr][lc4] = v.x; Ts[lr][lc4 + 1] = v.y; Ts[lr][lc4 + 2] = v.z; Ts[lr][lc4 + 3] = v.w;
    __syncthreads();
    const int oc = t >> 3, or4 = (t & 7) * 4;
    ushort4 o;
    o.x = f2bf(Ts[or4 + 0][oc]); o.y = f2bf(Ts[or4 + 1][oc]);
    o.z = f2bf(Ts[or4 + 2][oc]); o.w = f2bf(Ts[or4 + 3][oc]);
    *(ushort4*)&Out[(size_t)(c0 + oc) * R + r0 + or4] = o;
}

// ---------------- w1 = W_gat @ a1, w2 = W_gat @ a2 ----------------
__global__ __launch_bounds__(256) void w12_k(const float* __restrict__ W_gat,
                                             const float* __restrict__ a_gat,
                                             float* __restrict__ w1,
                                             float* __restrict__ w2)
{
    const int t = threadIdx.x;
    const int k = blockIdx.x * 4 + (t >> 6);
    const int l = t & 63;
    float4 wv = *(const float4*)&W_gat[(size_t)k * DM + 4 * l];
    float4 a1 = *(const float4*)&a_gat[4 * l];
    float4 a2 = *(const float4*)&a_gat[DM + 4 * l];
    float s1 = wv.x*a1.x + wv.y*a1.y + wv.z*a1.z + wv.w*a1.w;
    float s2 = wv.x*a2.x + wv.y*a2.y + wv.z*a2.z + wv.w*a2.w;
    #pragma unroll
    for (int off = 32; off; off >>= 1) {
        s1 += __shfl_xor(s1, off, 64);
        s2 += __shfl_xor(s2, off, 64);
    }
    if (l == 0) { w1[k] = s1; w2[k] = s2; }
}

// ---------------- f1 = log2e*(src@w1), f2 = log2e*(src@w2) ----------------
__global__ __launch_bounds__(256) void f12_k(const float* __restrict__ src,
                                             const float* __restrict__ w1,
                                             const float* __restrict__ w2,
                                             float* __restrict__ f1,
                                             float* __restrict__ f2)
{
    const int t = threadIdx.x;
    const size_t row = (size_t)blockIdx.x * 4 + (t >> 6);
    const int l = t & 63;
    float s1 = 0.f, s2 = 0.f;
    #pragma unroll
    for (int i = 0; i < 4; i++) {
        float v = src[row * DM + l + 64*i];
        s1 = fmaf(v, w1[l + 64*i], s1);
        s2 = fmaf(v, w2[l + 64*i], s2);
    }
    #pragma unroll
    for (int off = 32; off; off >>= 1) {
        s1 += __shfl_xor(s1, off, 64);
        s2 += __shfl_xor(s2, off, 64);
    }
    if (l == 0) { f1[row] = s1 * LOG2E; f2[row] = s2 * LOG2E; }
}

// ---------------- bf16 MFMA GEMM v2: reg-prefetch + dbuf LDS, 1 barrier/K-step ----------------
// C = act(A @ B^T + bias). A: (M,K). B rows at stride ldB. BM,BN in {64,128}.
// EP: 1 +bias->f32, 2 +bias,relu->bf16, 3 elu->f32, 5 plain->bf16, 6 qkv(+bias,Q-scaled)->bf16
template<int EP, int BM, int BN>
__global__ __launch_bounds__(256) void gemm_bf(const ushort* __restrict__ A,
                                               const ushort* __restrict__ B,
                                               const float* __restrict__ bias,
                                               float* __restrict__ Cf,
                                               ushort* __restrict__ Cb,
                                               int M, int N, int K, int ldB,
                                               long long sA, long long sB, long long sC)
{
    __shared__ ushort As[2][BM][40];
    __shared__ ushort Bs[2][BN][40];
    A += (size_t)blockIdx.z * sA;
    B += (size_t)blockIdx.z * sB;

    const int t  = threadIdx.x;
    const int m0 = blockIdx.y * BM, n0 = blockIdx.x * BN;
    const int lane = t & 63, lo = lane & 15, hi = lane >> 4;
    const int w = t >> 6;
    constexpr int NI = BM / 32, NJ = BN / 32;      // fragments per wave
    const int wr = (w >> 1) * (BM / 2);
    const int wc = (w & 1) * (BN / 2);

    const int lrA = (BM == 128) ? (t >> 1) : (t >> 2);
    const int lcA = (BM == 128) ? ((t & 1) * 16) : ((t & 3) * 8);
    const int lrB = (BN == 128) ? (t >> 1) : (t >> 2);
    const int lcB = (BN == 128) ? ((t & 1) * 16) : ((t & 3) * 8);

    f32x4 acc[NI][NJ];
    const f32x4 zero = {0.f, 0.f, 0.f, 0.f};
    #pragma unroll
    for (int i = 0; i < NI; i++)
        #pragma unroll
        for (int j = 0; j < NJ; j++) acc[i][j] = zero;

    const ushort* Ap = A + (size_t)(m0 + lrA) * K + lcA;
    const ushort* Bp = B + (size_t)(n0 + lrB) * ldB + lcB;

    // prologue: tile 0 -> regs -> LDS[0]
    short8 ar0, ar1, br0, br1;
    ar0 = *(const short8*)(Ap);
    if constexpr (BM == 128) ar1 = *(const short8*)(Ap + 8);
    br0 = *(const short8*)(Bp);
    if constexpr (BN == 128) br1 = *(const short8*)(Bp + 8);
    *(short8*)&As[0][lrA][lcA] = ar0;
    if constexpr (BM == 128) *(short8*)&As[0][lrA][lcA + 8] = ar1;
    *(short8*)&Bs[0][lrB][lcB] = br0;
    if constexpr (BN == 128) *(short8*)&Bs[0][lrB][lcB + 8] = br1;

    const int NT = K >> 5;
    for (int it = 0; it < NT; it++) {
        const int cur = it & 1;
        if (it + 1 < NT) {          // issue next tile's global loads early
            const int k0 = (it + 1) << 5;
            ar0 = *(const short8*)(Ap + k0);
            if constexpr (BM == 128) ar1 = *(const short8*)(Ap + k0 + 8);
            br0 = *(const short8*)(Bp + k0);
            if constexpr (BN == 128) br1 = *(const short8*)(Bp + k0 + 8);
        }
        __syncthreads();            // LDS[cur] writes visible; prev reads of LDS[cur^1] done

        short8 afr[NI], bfr[NJ];
        #pragma unroll
        for (int i = 0; i < NI; i++) afr[i] = *(const short8*)&As[cur][wr + i*16 + lo][hi * 8];
        #pragma unroll
        for (int j = 0; j < NJ; j++) bfr[j] = *(const short8*)&Bs[cur][wc + j*16 + lo][hi * 8];
        #pragma unroll
        for (int i = 0; i < NI; i++)
            #pragma unroll
            for (int j = 0; j < NJ; j++)
                acc[i][j] = __builtin_amdgcn_mfma_f32_16x16x32_bf16(afr[i], bfr[j], acc[i][j], 0, 0, 0);

        if (it + 1 < NT) {          // write next tile into other buffer
            *(short8*)&As[cur ^ 1][lrA][lcA] = ar0;
            if constexpr (BM == 128) *(short8*)&As[cur ^ 1][lrA][lcA + 8] = ar1;
            *(short8*)&Bs[cur ^ 1][lrB][lcB] = br0;
            if constexpr (BN == 128) *(short8*)&Bs[cur ^ 1][lrB][lcB + 8] = br1;
        }
    }

    if (EP == 2 || EP == 5 || EP == 6) Cb += (size_t)blockIdx.z * sC;
    else                               Cf += (size_t)blockIdx.z * sC;
    #pragma unroll
    for (int j = 0; j < NJ; j++) {
        const int col = n0 + wc + j * 16 + lo;
        float bj = (EP == 1 || EP == 2 || EP == 6) ? bias[col] : 0.f;
        #pragma unroll
        for (int i = 0; i < NI; i++) {
            const int rbase = m0 + wr + i * 16 + hi * 4;
            #pragma unroll
            for (int r = 0; r < 4; r++) {
                float v = acc[i][j][r] + bj;
                if (EP == 3) v = v > 0.f ? v : expm1f(v);
                if (EP == 2) v = fmaxf(v, 0.f);
                if (EP == 6 && col < DM) v *= QSCALE;
                if (EP == 2 || EP == 5 || EP == 6) Cb[(size_t)(rbase + r) * N + col] = f2bf(v);
                else                               Cf[(size_t)(rbase + r) * N + col] = v;
            }
        }
    }
}

// ---------------- LayerNorm(a + r) * g + b, 4 rows / block ----------------
template<bool WB>
__global__ __launch_bounds__(256) void ln_k(const float* __restrict__ a,
                                            const float* __restrict__ r,
                                            const float* __restrict__ g,
                                            const float* __restrict__ be,
                                            float* __restrict__ o,
                                            ushort* __restrict__ ob)
{
    const size_t row = (size_t)blockIdx.x * 4 + (threadIdx.x >> 6);
    const int l = threadIdx.x & 63;
    const float* pa = a + row * DM;
    const float* pr = r + row * DM;
    float v[4]; float s = 0.f;
    #pragma unroll
    for (int i = 0; i < 4; i++) { v[i] = pa[l + 64*i] + pr[l + 64*i]; s += v[i]; }
    #pragma unroll
    for (int off = 32; off; off >>= 1) s += __shfl_xor(s, off, 64);
    float mu = s * (1.0f / DM);
    float q = 0.f;
    #pragma unroll
    for (int i = 0; i < 4; i++) { float d = v[i] - mu; q += d * d; }
    #pragma unroll
    for (int off = 32; off; off >>= 1) q += __shfl_xor(q, off, 64);
    float rs = rsqrtf(q * (1.0f / DM) + EPSV);
    #pragma unroll
    for (int i = 0; i < 4; i++) {
        int c = l + 64*i;
        float out = (v[i] - mu) * rs * g[c] + be[c];
        o[row * DM + c] = out;
        if (WB) ob[row * DM + c] = f2bf(out);
    }
}

// ---------------- GAT masked softmax (exp2 domain) -> normalized P (bf16) ----------------
__global__ __launch_bounds__(256) void gat_sm_k(const int* __restrict__ adj,
                                                const float* __restrict__ f1,
                                                const float* __restrict__ f2,
                                                ushort* __restrict__ P)
{
    __shared__ float red[8];
    const int i = blockIdx.x, b = i >> 10;
    const int t = threadIdx.x;
    const int4 a4 = *(const int4*)&adj[(size_t)i * SEQ + 4 * t];
    const float4 f4 = *(const float4*)&f2[(size_t)(b << 10) + 4 * t];
    const float f1i = f1[i];
    float e[4];
    e[0] = a4.x > 0 ? f1i + f4.x : NEGV;
    e[1] = a4.y > 0 ? f1i + f4.y : NEGV;
    e[2] = a4.z > 0 ? f1i + f4.z : NEGV;
    e[3] = a4.w > 0 ? f1i + f4.w : NEGV;
    float mx = fmaxf(fmaxf(e[0], e[1]), fmaxf(e[2], e[3]));
    #pragma unroll
    for (int off = 32; off; off >>= 1) mx = fmaxf(mx, __shfl_xor(mx, off, 64));
    if ((t & 63) == 0) red[t >> 6] = mx;
    __syncthreads();
    mx = fmaxf(fmaxf(red[0], red[1]), fmaxf(red[2], red[3]));
    float s = 0.f;
    #pragma unroll
    for (int u = 0; u < 4; u++) { e[u] = exp2f(e[u] - mx); s += e[u]; }
    #pragma unroll
    for (int off = 32; off; off >>= 1) s += __shfl_xor(s, off, 64);
    if ((t & 63) == 0) red[4 + (t >> 6)] = s;
    __syncthreads();
    float inv = 1.0f / (red[4] + red[5] + red[6] + red[7]);
    ushort4 o;
    o.x = f2bf(e[0] * inv); o.y = f2bf(e[1] * inv);
    o.z = f2bf(e[2] * inv); o.w = f2bf(e[3] * inv);
    *(ushort4*)&P[(size_t)i * SEQ + 4 * t] = o;
}

// ---------------- MHA v4 (unchanged from round 7) ----------------
__device__ __forceinline__ int vt_idx(int d, int kv) { return d * 72 + ((d >> 3) & 3) * 16 + kv; }
constexpr int VTSZ = 32 * 72 + 3 * 16 + 8;

__global__ __launch_bounds__(256) void mha_k(const ushort* __restrict__ qkv,
                                             ushort* __restrict__ ctxb)
{
    __shared__ ushort Ks[2][64][40];
    __shared__ ushort Vt[2][VTSZ];
    __shared__ ushort Ps[64][72];

    const int blk = blockIdx.x;
    const int qt = blk & 15, h = (blk >> 4) & 7, b = blk >> 7;
    const int i0 = qt << 6;
    const int t = threadIdx.x;
    const int w = t >> 6, lane = t & 63, lo = lane & 15, hi = lane >> 4;
    const int gsh = lane & 48;
    const size_t base = (size_t)b * SEQ * 768;

    const short8 aQ = *(const short8*)(qkv + base + (size_t)(i0 + 16*w + lo) * 768 + h * HDIM + hi * 8);
    short8 ones;
    #pragma unroll
    for (int e = 0; e < 8; e++) ones[e] = (short)0x3F80;

    const int srow = t >> 2, scb = (t & 3) << 3;
    const int vcol = (srow & 32) | ((srow & 15) << 1) | ((srow >> 4) & 1);
    {
        const ushort* p0 = qkv + base + (size_t)srow * 768 + h * HDIM;
        short8 k0 = *(const short8*)(p0 + 256 + scb);
        short8 v0 = *(const short8*)(p0 + 512 + scb);
        *(short8*)&Ks[0][srow][scb] = k0;
        #pragma unroll
        for (int e = 0; e < 8; e++) Vt[0][vt_idx(scb + e, vcol)] = (ushort)v0[e];
    }

    float m_run[4], l_run[4];
    f32x4 O0 = {0.f, 0.f, 0.f, 0.f}, O1 = {0.f, 0.f, 0.f, 0.f};
    #pragma unroll
    for (int r = 0; r < 4; r++) { m_run[r] = -3.0e38f; l_run[r] = 0.f; }
    const f32x4 zero = {0.f, 0.f, 0.f, 0.f};

    short8 kreg, vreg;
    for (int it = 0; it < 16; it++) {
        const int cur = it & 1;
        if (it < 15) {
            const ushort* nb = qkv + base + (size_t)((it + 1) * 64 + srow) * 768 + h * HDIM;
            kreg = *(const short8*)(nb + 256 + scb);
            vreg = *(const short8*)(nb + 512 + scb);
        }
        __syncthreads();

        f32x4 S[4];
        #pragma unroll
        for (int jt = 0; jt < 4; jt++) {
            short8 bK = *(const short8*)&Ks[cur][16 * jt + lo][hi * 8];
            S[jt] = __builtin_amdgcn_mfma_f32_16x16x32_bf16(aQ, bK, zero, 0, 0, 0);
        }

        float mxl[4];
        bool any = false;
        #pragma unroll
        for (int r = 0; r < 4; r++) {
            mxl[r] = fmaxf(fmaxf(S[0][r], S[1][r]), fmaxf(S[2][r], S[3][r]));
            any = any || (mxl[r] > m_run[r] + 8.f);
        }
        unsigned long long bal = __ballot(any);
        if ((bal >> gsh) & 0xffffULL) {
            #pragma unroll
            for (int r = 0; r < 4; r++) {
                float mx = mxl[r];
                #pragma unroll
                for (int off = 8; off; off >>= 1) mx = fmaxf(mx, __shfl_xor(mx, off, 16));
                float mnew = fmaxf(m_run[r], mx);
                float sc = exp2f(m_run[r] - mnew);
                m_run[r] = mnew;
                l_run[r] *= sc; O0[r] *= sc; O1[r] *= sc;
            }
        }
        #pragma unroll
        for (int r = 0; r < 4; r++) {
            const int row = 16 * w + 4 * hi + r;
            unsigned u01 = cvt_pk_bf16(exp2f(S[0][r] - m_run[r]), exp2f(S[1][r] - m_run[r]));
            unsigned u23 = cvt_pk_bf16(exp2f(S[2][r] - m_run[r]), exp2f(S[3][r] - m_run[r]));
            *(unsigned*)&Ps[row][2 * lo]      = u01;
            *(unsigned*)&Ps[row][32 + 2 * lo] = u23;
        }

        f32x4 O2 = zero;
        #pragma unroll
        for (int kt = 0; kt < 2; kt++) {
            short8 aP  = *(const short8*)&Ps[16 * w + lo][32 * kt + hi * 8];
            short8 bV0 = *(const short8*)&Vt[cur][vt_idx(lo,      32 * kt + hi * 8)];
            short8 bV1 = *(const short8*)&Vt[cur][vt_idx(16 + lo, 32 * kt + hi * 8)];
            O0 = __builtin_amdgcn_mfma_f32_16x16x32_bf16(aP, bV0, O0, 0, 0, 0);
            O1 = __builtin_amdgcn_mfma_f32_16x16x32_bf16(aP, bV1, O1, 0, 0, 0);
            O2 = __builtin_amdgcn_mfma_f32_16x16x32_bf16(aP, ones, O2, 0, 0, 0);
        }
        #pragma unroll
        for (int r = 0; r < 4; r++) l_run[r] += O2[r];

        if (it < 15) {
            *(short8*)&Ks[cur ^ 1][srow][scb] = kreg;
            #pragma unroll
            for (int e = 0; e < 8; e++) Vt[cur ^ 1][vt_idx(scb + e, vcol)] = (ushort)vreg[e];
        }
    }

    #pragma unroll
    for (int r = 0; r < 4; r++) {
        float inv = 1.0f / l_run[r];
        size_t row = (size_t)b * SEQ + i0 + 16 * w + 4 * hi + r;
        ctxb[row * DM + h * HDIM + lo]      = f2bf(O0[r] * inv);
        ctxb[row * DM + h * HDIM + 16 + lo] = f2bf(O1[r] * inv);
    }
}

extern "C" void kernel_launch(void* const* d_in, const int* in_sizes, int n_in,
                              void* d_out, int out_size, void* d_ws, size_t ws_size,
                              hipStream_t stream)
{
    const float* src        = (const float*)d_in[0];
    const int*   adj        = (const int*)  d_in[1];
    const float* W_gat      = (const float*)d_in[2];
    const float* a_gat      = (const float*)d_in[3];
    const float* in_proj_w  = (const float*)d_in[4];
    const float* in_proj_b  = (const float*)d_in[5];
    const float* out_proj_w = (const float*)d_in[6];
    const float* out_proj_b = (const float*)d_in[7];
    const float* lin1_w     = (const float*)d_in[8];
    const float* lin1_b     = (const float*)d_in[9];
    const float* lin2_w     = (const float*)d_in[10];
    const float* lin2_b     = (const float*)d_in[11];
    const float* ln1_g      = (const float*)d_in[12];
    const float* ln1_b_     = (const float*)d_in[13];
    const float* ln2_g      = (const float*)d_in[14];
    const float* ln2_b_     = (const float*)d_in[15];
    const float* ln3_g      = (const float*)d_in[16];
    const float* ln3_b_     = (const float*)d_in[17];

    char* base = (char*)d_ws;
    const size_t MB = 1024 * 1024;
    float*  tmp   = (float*) (base + 0 * MB);
    float*  x     = (float*) (base + 8 * MB);
    float*  y     = (float*) (base + 16 * MB);
    ushort* P_bf  = (ushort*)(base + 24 * MB);
    ushort* qkvb  = (ushort*)(base + 24 * MB);
    ushort* ff1b  = (ushort*)(base + 24 * MB);
    ushort* srcb  = (ushort*)(base + 56 * MB);
    ushort* WhTb  = (ushort*)(base + 60 * MB);
    ushort* xb    = (ushort*)(base + 64 * MB);
    ushort* yb    = (ushort*)(base + 68 * MB);
    ushort* ctxb  = (ushort*)(base + 72 * MB);
    float*  f1    = (float*) (base + 76 * MB);
    float*  f2    = f1 + ROWS;
    float*  w1    = f2 + ROWS;
    float*  w2    = w1 + DM;
    ushort* wgTb  = (ushort*)(base + 77 * MB);
    ushort* ipwb  = wgTb + 65536;
    ushort* opwb  = ipwb + 196608;
    ushort* l1wb  = opwb + 65536;
    ushort* l2wb  = l1wb + 524288;

    dim3 b256(256);

    CastArgs ca;
    ca.in[0] = src;       ca.out[0] = srcb; ca.n4[0] = 2097152 / 4;
    ca.in[1] = in_proj_w; ca.out[1] = ipwb; ca.n4[1] = 196608 / 4;
    ca.in[2] = out_proj_w;ca.out[2] = opwb; ca.n4[2] = 65536 / 4;
    ca.in[3] = lin1_w;    ca.out[3] = l1wb; ca.n4[3] = 524288 / 4;
    ca.in[4] = lin2_w;    ca.out[4] = l2wb; ca.n4[4] = 524288 / 4;
    castall_k<<<(2097152 + 196608 + 65536 + 524288 + 524288) / 4 / 256, b256, 0, stream>>>(ca);
    tcast_k<<<dim3(8, 8), b256, 0, stream>>>(W_gat, wgTb, 256, 256);

    // --- GAT ---
    w12_k<<<64, b256, 0, stream>>>(W_gat, a_gat, w1, w2);
    f12_k<<<ROWS / 4, b256, 0, stream>>>(src, w1, w2, f1, f2);
    // WhT = W_gat^T @ src^T -> bf16 [256][8192]
    gemm_bf<5, 64, 64><<<dim3(ROWS/64, DM/64, 1), b256, 0, stream>>>(wgTb, srcb, nullptr, nullptr, WhTb,
                                                                     DM, ROWS, DM, DM, 0, 0, 0);
    gat_sm_k<<<ROWS, b256, 0, stream>>>(adj, f1, f2, P_bf);
    gemm_bf<3, 64, 64><<<dim3(DM/64, SEQ/64, 8), b256, 0, stream>>>(P_bf, WhTb, nullptr, tmp, nullptr,
                                                                    SEQ, DM, SEQ, ROWS,
                                                                    (long long)SEQ * SEQ, (long long)SEQ, (long long)SEQ * DM);
    ln_k<true><<<ROWS / 4, b256, 0, stream>>>(src, tmp, ln1_g, ln1_b_, x, xb);

    // --- MHA ---
    gemm_bf<6, 128, 128><<<dim3(6, 64, 1), b256, 0, stream>>>(xb, ipwb, in_proj_b, nullptr, qkvb,
                                                              ROWS, 768, DM, DM, 0, 0, 0);
    mha_k<<<BATCH * NH * (SEQ / 64), b256, 0, stream>>>(qkvb, ctxb);
    gemm_bf<1, 64, 64><<<dim3(DM/64, ROWS/64, 1), b256, 0, stream>>>(ctxb, opwb, out_proj_b, tmp, nullptr,
                                                                     ROWS, DM, DM, DM, 0, 0, 0);
    ln_k<true><<<ROWS / 4, b256, 0, stream>>>(x, tmp, ln2_g, ln2_b_, y, yb);

    // --- FFN ---
    gemm_bf<2, 128, 128><<<dim3(16, 64, 1), b256, 0, stream>>>(yb, l1wb, lin1_b, nullptr, ff1b,
                                                               ROWS, DF, DM, DM, 0, 0, 0);
    gemm_bf<1, 64, 64><<<dim3(DM/64, ROWS/64, 1), b256, 0, stream>>>(ff1b, l2wb, lin2_b, tmp, nullptr,
                                                                     ROWS, DM, DF, DF, 0, 0, 0);
    ln_k<false><<<ROWS / 4, b256, 0, stream>>>(y, tmp, ln3_g, ln3_b_, (float*)d_out, nullptr);
}